// Round 1
// baseline (2137.524 us; speedup 1.0000x reference)
//
#include <hip/hip_runtime.h>
#include <hip/hip_bf16.h>
#include <math.h>

#define B_ 4
#define S_ 2048
#define D_ 768
#define H_ 12
#define HD_ 64
#define P_ 768
#define M_ (B_*S_)   // 8192

typedef __hip_bfloat16 bf16;
typedef __attribute__((ext_vector_type(8))) short short8;
typedef __attribute__((ext_vector_type(4))) float f32x4;

__device__ __forceinline__ float wave_reduce_sum(float v){
  #pragma unroll
  for (int off=32; off>0; off>>=1) v += __shfl_xor(v, off, 64);
  return v;
}

// ---------------- weight packing ----------------
__global__ __launch_bounds__(256) void pack_wh_kernel(const float* __restrict__ km, const float* __restrict__ vm,
                                                      const float* __restrict__ qm, bf16* __restrict__ out){
  int i = blockIdx.x*256 + threadIdx.x; // < 640*768 (padded to 640 rows)
  if (i >= 640*768) return;
  int r = i/768, c = i%768;
  float v = 0.f;
  if (r < 192) v = km[r*768+c];
  else if (r < 384) v = vm[(r-192)*768+c];
  else if (r < 576) v = qm[(r-384)*768+c];
  out[i] = __float2bfloat16(v);
}

__global__ __launch_bounds__(256) void pack_wkvq_kernel(const float* __restrict__ Wk,const float* __restrict__ Wv,
                                                        const float* __restrict__ Wq,const float* __restrict__ k2,
                                                        const float* __restrict__ v2,const float* __restrict__ q2,
                                                        bf16* __restrict__ out){
  int i = blockIdx.x*256 + threadIdx.x; // < 2304*960
  if (i >= 2304*960) return;
  int r = i/960, c = i%960;
  int p = r/768, rr = r%768;
  const float* W  = (p==0)?Wk:(p==1)?Wv:Wq;
  const float* w2 = (p==0)?k2:(p==1)?v2:q2;
  float v = (c < 768) ? W[(size_t)rr*768+c] : 0.1f*w2[(size_t)rr*192 + (c-768)];
  out[i] = __float2bfloat16(v);
}

__global__ __launch_bounds__(256) void pack_cast_kernel(const float* __restrict__ src, bf16* __restrict__ dst, int n){
  int i = blockIdx.x*256 + threadIdx.x;
  if (i < n) dst[i] = __float2bfloat16(src[i]);
}

__global__ __launch_bounds__(256) void pack_bias_kernel(const float* __restrict__ kb1,const float* __restrict__ vb1,
                                                        const float* __restrict__ qb1,const float* __restrict__ kb2,
                                                        const float* __restrict__ vb2,const float* __restrict__ qb2,
                                                        float* __restrict__ out){
  int i = blockIdx.x*256 + threadIdx.x;
  if (i >= 2880) return;
  if (i < 576){
    out[i] = (i<192)? kb1[i] : (i<384)? vb1[i-192] : qb1[i-384];
  } else {
    int r = i-576; int p = r/768, rr = r%768;
    const float* b2 = (p==0)?kb2:(p==1)?vb2:qb2;
    out[i] = 0.1f*b2[rr];
  }
}

// ---------------- input layernorm ----------------
__global__ __launch_bounds__(256) void ln_in_kernel(const float* __restrict__ x, const float* __restrict__ g,
                                                    const float* __restrict__ bta,
                                                    bf16* __restrict__ xn, bf16* __restrict__ xb){
  int row = blockIdx.x;
  const float* xr = x + (size_t)row*D_;
  int t = threadIdx.x;
  float v0 = xr[t], v1 = xr[t+256], v2 = xr[t+512];
  float s  = v0+v1+v2;
  float sq = v0*v0+v1*v1+v2*v2;
  s = wave_reduce_sum(s); sq = wave_reduce_sum(sq);
  __shared__ float red[8];
  int w = t>>6;
  if ((t&63)==0){ red[w]=s; red[4+w]=sq; }
  __syncthreads();
  s  = red[0]+red[1]+red[2]+red[3];
  sq = red[4]+red[5]+red[6]+red[7];
  float mean = s*(1.f/D_);
  float var  = sq*(1.f/D_) - mean*mean;
  float inv  = rsqrtf(var + 1e-5f);
  bf16* xnr = xn + (size_t)row*D_;
  bf16* xbr = xb + (size_t)row*D_;
  xnr[t]     = __float2bfloat16((v0-mean)*inv*g[t]     + bta[t]);
  xnr[t+256] = __float2bfloat16((v1-mean)*inv*g[t+256] + bta[t+256]);
  xnr[t+512] = __float2bfloat16((v2-mean)*inv*g[t+512] + bta[t+512]);
  xbr[t] = __float2bfloat16(v0); xbr[t+256] = __float2bfloat16(v1); xbr[t+512] = __float2bfloat16(v2);
}

// ---------------- GEMM (bf16 MFMA, 128x128 tile, BK=32, 4 waves 2x2) ----------------
// C[m][n] = sum_k A[m][k] * Bw[n][k]   (both K-contiguous row-major)
// A: k<K1 from A1; k>=K1 from A2 (col offset g*a2_gstride). B rows offset by g*ngroup.
// MODE 0: gelu(val+bias[n]) -> bf16 [M][Nout]
// MODE 1: val+bias[g*768+n] -> fp32 scatter to [g][b][h][s][hd]
// MODE 2: val -> fp32 [M][Nout]
template<int MODE>
__global__ __launch_bounds__(256) void gemm_kernel(
    const bf16* __restrict__ A1, int lda1, int K1,
    const bf16* __restrict__ A2, int lda2, int K2, int a2_gstride,
    const bf16* __restrict__ Bw, int ldb, int ngroup,
    const float* __restrict__ bias,
    void* __restrict__ outp, int Nout)
{
  __shared__ bf16 Asm[128*32];
  __shared__ bf16 Bsm[128*32];
  const int t = threadIdx.x;
  const int w = t>>6, L = t&63;
  const int m0 = blockIdx.x*128, n0 = blockIdx.y*128;
  const int g = blockIdx.z;
  const int wm = w>>1, wn = w&1;
  const int srow = t>>1;          // 0..127
  const int scol = (t&1)*16;      // 0 or 16
  const int Ktot = K1 + K2;

  f32x4 acc[4][4];
  #pragma unroll
  for (int i=0;i<4;i++)
    #pragma unroll
    for (int j=0;j<4;j++) acc[i][j] = (f32x4){0.f,0.f,0.f,0.f};

  const bf16* Brow = Bw + ((size_t)(g*ngroup + n0 + srow))*ldb;

  for (int k0=0; k0<Ktot; k0+=32){
    short8 a0,a1,b0,b1;
    if (k0 < K1){
      const bf16* ap = A1 + (size_t)(m0+srow)*lda1 + k0 + scol;
      a0 = *(const short8*)ap; a1 = *(const short8*)(ap+8);
    } else {
      const bf16* ap = A2 + (size_t)(m0+srow)*lda2 + (k0-K1) + g*a2_gstride + scol;
      a0 = *(const short8*)ap; a1 = *(const short8*)(ap+8);
    }
    {
      const bf16* bp = Brow + k0 + scol;
      b0 = *(const short8*)bp; b1 = *(const short8*)(bp+8);
    }
    __syncthreads();  // protect previous tile's reads
    *(short8*)&Asm[srow*32+scol]   = a0; *(short8*)&Asm[srow*32+scol+8] = a1;
    *(short8*)&Bsm[srow*32+scol]   = b0; *(short8*)&Bsm[srow*32+scol+8] = b1;
    __syncthreads();
    short8 af[4], bfr[4];
    #pragma unroll
    for (int f=0;f<4;f++){
      af[f]  = *(const short8*)&Asm[(wm*64 + f*16 + (L&15))*32 + (L>>4)*8];
      bfr[f] = *(const short8*)&Bsm[(wn*64 + f*16 + (L&15))*32 + (L>>4)*8];
    }
    #pragma unroll
    for (int i=0;i<4;i++)
      #pragma unroll
      for (int j=0;j<4;j++)
        acc[i][j] = __builtin_amdgcn_mfma_f32_16x16x32_bf16(af[i], bfr[j], acc[i][j], 0,0,0);
  }

  #pragma unroll
  for (int i=0;i<4;i++){
    #pragma unroll
    for (int j=0;j<4;j++){
      #pragma unroll
      for (int r=0;r<4;r++){
        int m = m0 + wm*64 + i*16 + (L>>4)*4 + r;
        int n = n0 + wn*64 + j*16 + (L&15);
        float val = acc[i][j][r];
        if (MODE==0){
          if (n < Nout){
            val += bias[n];
            float ge = 0.5f*val*(1.f + erff(val*0.70710678f));
            ((bf16*)outp)[(size_t)m*Nout + n] = __float2bfloat16(ge);
          }
        } else if (MODE==1){
          val += bias[g*768 + n];
          int b_ = m>>11, s_ = m&2047, h_ = n>>6, hd = n&63;
          ((float*)outp)[((((size_t)g*B_ + b_)*H_ + h_)*S_ + s_)*HD_ + hd] = val;
        } else {
          ((float*)outp)[(size_t)m*Nout + n] = val;
        }
      }
    }
  }
}

// ---------------- per-head LN (+ k normalization), in place ----------------
__global__ __launch_bounds__(256) void headln_kernel(float* __restrict__ kvqs,
    const float* __restrict__ lnk_g, const float* __restrict__ lnk_b,
    const float* __restrict__ lnv_g, const float* __restrict__ lnv_b,
    const float* __restrict__ lnq_g, const float* __restrict__ lnq_b){
  int wid = threadIdx.x>>6, lane = threadIdx.x&63;
  size_t r = (size_t)blockIdx.x*4 + wid;       // total rows = 3*B*H*S = 294912
  float* p = kvqs + r*HD_;
  int proj = (int)(r / ((size_t)B_*H_*S_));
  const float* gp; const float* bp;
  if (proj==0){ gp=lnk_g; bp=lnk_b; } else if (proj==1){ gp=lnv_g; bp=lnv_b; } else { gp=lnq_g; bp=lnq_b; }
  float v = p[lane];
  float mean = wave_reduce_sum(v) * (1.f/64.f);
  float d = v - mean;
  float var = wave_reduce_sum(d*d) * (1.f/64.f);
  float y = d * rsqrtf(var + 1e-5f) * gp[lane] + bp[lane];
  if (proj==0){
    float n2 = wave_reduce_sum(y*y);
    y = y / (sqrtf(n2) + 1e-6f);
  }
  p[lane] = y;
}

// ---------------- sequential delta-rule scan: 1 wave per (b,h) ----------------
__global__ __launch_bounds__(64) void scan_kernel(
    const float* __restrict__ kvqs, const float* __restrict__ lr_scale,
    bf16* __restrict__ attn, float* __restrict__ Mout){
  int b = blockIdx.x / H_, h = blockIdx.x % H_;
  int lane = threadIdx.x;
  const size_t PS = (size_t)B_*H_*S_*HD_;
  const float* kp = kvqs + ((size_t)(b*H_ + h))*S_*HD_;
  const float* vp = kp + PS;
  const float* qp = kp + 2*PS;
  float lr = 0.2f * (1.f/(1.f + __expf(-lr_scale[h])));
  float beta = 1.f + lr;
  float Mr[64];
  #pragma unroll
  for (int i=0;i<64;i++) Mr[i]=0.f;
  __shared__ float sh[2][2][64];
  float kc = kp[lane], vc = vp[lane], qc = qp[lane];
  bf16* ao = attn + (size_t)b*S_*P_ + h*HD_ + lane;
  for (int s=0; s<S_; s++){
    int buf = s&1;
    sh[buf][0][lane] = kc; sh[buf][1][lane] = qc;
    float vcur = vc;
    if (s+1 < S_){
      kc = kp[(size_t)(s+1)*HD_ + lane];
      vc = vp[(size_t)(s+1)*HD_ + lane];
      qc = qp[(size_t)(s+1)*HD_ + lane];
    }
    __syncthreads();
    const float4* kl = (const float4*)sh[buf][0];
    const float4* ql = (const float4*)sh[buf][1];
    float4 kv[16], qv[16];
    #pragma unroll
    for (int i=0;i<16;i++){ kv[i]=kl[i]; qv[i]=ql[i]; }
    float o0=0,o1=0,o2=0,o3=0,p0=0,p1=0,p2=0,p3=0;
    #pragma unroll
    for (int i=0;i<16;i++){
      o0 += Mr[4*i+0]*qv[i].x; p0 += Mr[4*i+0]*kv[i].x;
      o1 += Mr[4*i+1]*qv[i].y; p1 += Mr[4*i+1]*kv[i].y;
      o2 += Mr[4*i+2]*qv[i].z; p2 += Mr[4*i+2]*kv[i].z;
      o3 += Mr[4*i+3]*qv[i].w; p3 += Mr[4*i+3]*kv[i].w;
    }
    float out  = (o0+o1)+(o2+o3);
    float pred = (p0+p1)+(p2+p3);
    ao[(size_t)s*P_] = __float2bfloat16(out);
    float nco = -(beta*pred - lr*vcur);  // -coef
    #pragma unroll
    for (int i=0;i<16;i++){
      Mr[4*i+0] += nco*kv[i].x;
      Mr[4*i+1] += nco*kv[i].y;
      Mr[4*i+2] += nco*kv[i].z;
      Mr[4*i+3] += nco*kv[i].w;
    }
  }
  float* mo = Mout + ((size_t)(b*H_ + h)*HD_ + lane)*HD_;
  #pragma unroll
  for (int i=0;i<16;i++) ((float4*)mo)[i] = make_float4(Mr[4*i],Mr[4*i+1],Mr[4*i+2],Mr[4*i+3]);
}

// ---------------- final gate*proj combine ----------------
__global__ __launch_bounds__(256) void combine_kernel(const float* __restrict__ G1, const float* __restrict__ G2,
                                                      const float* __restrict__ bg, float* __restrict__ out){
  size_t i = (size_t)blockIdx.x*256 + threadIdx.x;
  if (i >= (size_t)M_*D_/4) return;
  float4 a = ((const float4*)G1)[i];
  float4 c = ((const float4*)G2)[i];
  int n = (int)((i*4) % D_);
  float4 r;
  r.x = a.x / (1.f + __expf(-(c.x + bg[n+0])));
  r.y = a.y / (1.f + __expf(-(c.y + bg[n+1])));
  r.z = a.z / (1.f + __expf(-(c.z + bg[n+2])));
  r.w = a.w / (1.f + __expf(-(c.w + bg[n+3])));
  ((float4*)out)[i] = r;
}

extern "C" void kernel_launch(void* const* d_in, const int* in_sizes, int n_in,
                              void* d_out, int out_size, void* d_ws, size_t ws_size,
                              hipStream_t stream)
{
  const float* x     = (const float*)d_in[0];
  const float* ln_g  = (const float*)d_in[1];
  const float* ln_b  = (const float*)d_in[2];
  const float* Wk    = (const float*)d_in[3];
  const float* Wv    = (const float*)d_in[4];
  const float* Wq    = (const float*)d_in[5];
  const float* km_w1 = (const float*)d_in[6];  const float* km_b1 = (const float*)d_in[7];
  const float* km_w2 = (const float*)d_in[8];  const float* km_b2 = (const float*)d_in[9];
  const float* vm_w1 = (const float*)d_in[10]; const float* vm_b1 = (const float*)d_in[11];
  const float* vm_w2 = (const float*)d_in[12]; const float* vm_b2 = (const float*)d_in[13];
  const float* qm_w1 = (const float*)d_in[14]; const float* qm_b1 = (const float*)d_in[15];
  const float* qm_w2 = (const float*)d_in[16]; const float* qm_b2 = (const float*)d_in[17];
  const float* lnk_g = (const float*)d_in[18]; const float* lnk_b = (const float*)d_in[19];
  const float* lnv_g = (const float*)d_in[20]; const float* lnv_b = (const float*)d_in[21];
  const float* lnq_g = (const float*)d_in[22]; const float* lnq_b = (const float*)d_in[23];
  const float* Wo    = (const float*)d_in[24];
  const float* lr_sc = (const float*)d_in[25];
  const float* Wg    = (const float*)d_in[26];
  const float* bg    = (const float*)d_in[27];

  char* ws = (char*)d_ws;
  size_t o = 0;
  bf16* xnb  = (bf16*)(ws + o); o += (size_t)M_*D_*2;           // 12.58 MB
  bf16* xb   = (bf16*)(ws + o); o += (size_t)M_*D_*2;           // 12.58 MB
  bf16* Hb   = (bf16*)(ws + o); o += (size_t)M_*576*2;          // 9.44 MB
  float* kvq = (float*)(ws + o); size_t o_kvq = o; o += (size_t)3*M_*P_*4; // 75.5 MB
  bf16* attn = (bf16*)(ws + o); o += (size_t)M_*P_*2;           // 12.58 MB
  bf16* Whb  = (bf16*)(ws + o); o += (size_t)640*768*2;
  bf16* Wkvqb= (bf16*)(ws + o); o += (size_t)2304*960*2;
  bf16* Wob  = (bf16*)(ws + o); o += (size_t)768*768*2;
  bf16* Wgb  = (bf16*)(ws + o); o += (size_t)768*768*2;
  float* biasb = (float*)(ws + o); o += 2880*4;
  // G1/G2 reuse the kvq region (dead after scan)
  float* G1 = (float*)(ws + o_kvq);
  float* G2 = (float*)(ws + o_kvq + (size_t)M_*D_*4);

  float* outF = (float*)d_out;
  float* Mout = outF + (size_t)M_*D_;

  pack_wh_kernel  <<<1920, 256, 0, stream>>>(km_w1, vm_w1, qm_w1, Whb);
  pack_wkvq_kernel<<<8640, 256, 0, stream>>>(Wk, Wv, Wq, km_w2, vm_w2, qm_w2, Wkvqb);
  pack_cast_kernel<<<2304, 256, 0, stream>>>(Wo, Wob, 768*768);
  pack_cast_kernel<<<2304, 256, 0, stream>>>(Wg, Wgb, 768*768);
  pack_bias_kernel<<<12, 256, 0, stream>>>(km_b1, vm_b1, qm_b1, km_b2, vm_b2, qm_b2, biasb);

  ln_in_kernel<<<M_, 256, 0, stream>>>(x, ln_g, ln_b, xnb, xb);

  // H = gelu(xn @ Wh^T + bh)  : M=8192, N=640(pad, 576 real), K=768
  gemm_kernel<0><<<dim3(64,5,1), 256, 0, stream>>>(xnb, 768, 768, nullptr, 0, 0, 0,
                                                   Whb, 768, 640, biasb, Hb, 576);
  // kvq = [xn|h_g] @ Wkvq^T + b : per group g in {k,v,q}, K=768+192, N=768, scatter to scan layout
  gemm_kernel<1><<<dim3(64,6,3), 256, 0, stream>>>(xnb, 768, 768, Hb, 576, 192, 192,
                                                   Wkvqb, 960, 768, biasb + 576, kvq, 768);

  headln_kernel<<<73728, 256, 0, stream>>>(kvq, lnk_g, lnk_b, lnv_g, lnv_b, lnq_g, lnq_b);

  scan_kernel<<<B_*H_, 64, 0, stream>>>(kvq, lr_sc, attn, Mout);

  // G1 = attn @ Wo^T ; G2 = x @ Wg^T
  gemm_kernel<2><<<dim3(64,6,1), 256, 0, stream>>>(attn, 768, 768, nullptr, 0, 0, 0,
                                                   Wob, 768, 768, nullptr, G1, 768);
  gemm_kernel<2><<<dim3(64,6,1), 256, 0, stream>>>(xb, 768, 768, nullptr, 0, 0, 0,
                                                   Wgb, 768, 768, nullptr, G2, 768);

  combine_kernel<<<6144, 256, 0, stream>>>(G1, G2, bg, outF);
}

// Round 2
// 438.123 us; speedup vs baseline: 4.8788x; 4.8788x over previous
//
#include <hip/hip_runtime.h>
#include <hip/hip_bf16.h>
#include <math.h>

#define B_ 4
#define S_ 2048
#define D_ 768
#define H_ 12
#define HD_ 64
#define P_ 768
#define M_ (B_*S_)   // 8192
#define NCH 32       // chunks per sequence
#define CH 64        // chunk length
#define BH (B_*H_)   // 48

typedef __hip_bfloat16 bf16;
typedef __attribute__((ext_vector_type(8))) short short8;
typedef __attribute__((ext_vector_type(4))) short s16x4;
typedef __attribute__((ext_vector_type(4))) float f32x4;

__device__ __forceinline__ float wave_reduce_sum(float v){
  #pragma unroll
  for (int off=32; off>0; off>>=1) v += __shfl_xor(v, off, 64);
  return v;
}
__device__ __forceinline__ float bf2f(bf16 h){ return __bfloat162float(h); }
__device__ __forceinline__ float us2f(unsigned short u){
  union{unsigned int i; float f;} z; z.i = ((unsigned int)u)<<16; return z.f;
}
__device__ __forceinline__ unsigned short f2us(float f){
  bf16 h = __float2bfloat16(f); return *(unsigned short*)&h;
}
// swizzled LDS access for [R][64] bf16 tiles (128B rows): byte ^= (row&7)<<4
__device__ __forceinline__ short8 lfrag(const char* base, int row, int col){
  return *(const short8*)(base + ((row*128 + col*2) ^ ((row&7)<<4)));
}

// ---------------- weight packing ----------------
__global__ __launch_bounds__(256) void pack_wh_kernel(const float* __restrict__ km, const float* __restrict__ vm,
                                                      const float* __restrict__ qm, bf16* __restrict__ out){
  int i = blockIdx.x*256 + threadIdx.x;
  if (i >= 640*768) return;
  int r = i/768, c = i%768;
  float v = 0.f;
  if (r < 192) v = km[r*768+c];
  else if (r < 384) v = vm[(r-192)*768+c];
  else if (r < 576) v = qm[(r-384)*768+c];
  out[i] = __float2bfloat16(v);
}

__global__ __launch_bounds__(256) void pack_wkvq_kernel(const float* __restrict__ Wk,const float* __restrict__ Wv,
                                                        const float* __restrict__ Wq,const float* __restrict__ k2,
                                                        const float* __restrict__ v2,const float* __restrict__ q2,
                                                        bf16* __restrict__ out){
  int i = blockIdx.x*256 + threadIdx.x;
  if (i >= 2304*960) return;
  int r = i/960, c = i%960;
  int p = r/768, rr = r%768;
  const float* W  = (p==0)?Wk:(p==1)?Wv:Wq;
  const float* w2 = (p==0)?k2:(p==1)?v2:q2;
  float v = (c < 768) ? W[(size_t)rr*768+c] : 0.1f*w2[(size_t)rr*192 + (c-768)];
  out[i] = __float2bfloat16(v);
}

__global__ __launch_bounds__(256) void pack_cast_kernel(const float* __restrict__ src, bf16* __restrict__ dst, int n){
  int i = blockIdx.x*256 + threadIdx.x;
  if (i < n) dst[i] = __float2bfloat16(src[i]);
}

__global__ __launch_bounds__(256) void pack_bias_kernel(const float* __restrict__ kb1,const float* __restrict__ vb1,
                                                        const float* __restrict__ qb1,const float* __restrict__ kb2,
                                                        const float* __restrict__ vb2,const float* __restrict__ qb2,
                                                        float* __restrict__ out){
  int i = blockIdx.x*256 + threadIdx.x;
  if (i >= 2880) return;
  if (i < 576){
    out[i] = (i<192)? kb1[i] : (i<384)? vb1[i-192] : qb1[i-384];
  } else {
    int r = i-576; int p = r/768, rr = r%768;
    const float* b2 = (p==0)?kb2:(p==1)?vb2:qb2;
    out[i] = 0.1f*b2[rr];
  }
}

// ---------------- input layernorm ----------------
__global__ __launch_bounds__(256) void ln_in_kernel(const float* __restrict__ x, const float* __restrict__ g,
                                                    const float* __restrict__ bta,
                                                    bf16* __restrict__ xn, bf16* __restrict__ xb){
  int row = blockIdx.x;
  const float* xr = x + (size_t)row*D_;
  int t = threadIdx.x;
  float v0 = xr[t], v1 = xr[t+256], v2 = xr[t+512];
  float s  = v0+v1+v2;
  float sq = v0*v0+v1*v1+v2*v2;
  s = wave_reduce_sum(s); sq = wave_reduce_sum(sq);
  __shared__ float red[8];
  int w = t>>6;
  if ((t&63)==0){ red[w]=s; red[4+w]=sq; }
  __syncthreads();
  s  = red[0]+red[1]+red[2]+red[3];
  sq = red[4]+red[5]+red[6]+red[7];
  float mean = s*(1.f/D_);
  float var  = sq*(1.f/D_) - mean*mean;
  float inv  = rsqrtf(var + 1e-5f);
  bf16* xnr = xn + (size_t)row*D_;
  bf16* xbr = xb + (size_t)row*D_;
  xnr[t]     = __float2bfloat16((v0-mean)*inv*g[t]     + bta[t]);
  xnr[t+256] = __float2bfloat16((v1-mean)*inv*g[t+256] + bta[t+256]);
  xnr[t+512] = __float2bfloat16((v2-mean)*inv*g[t+512] + bta[t+512]);
  xbr[t] = __float2bfloat16(v0); xbr[t+256] = __float2bfloat16(v1); xbr[t+512] = __float2bfloat16(v2);
}

// ---------------- GEMM (bf16 MFMA, 128x128 tile, BK=32, 4 waves 2x2) ----------------
template<int MODE>
__global__ __launch_bounds__(256) void gemm_kernel(
    const bf16* __restrict__ A1, int lda1, int K1,
    const bf16* __restrict__ A2, int lda2, int K2, int a2_gstride,
    const bf16* __restrict__ Bw, int ldb, int ngroup,
    const float* __restrict__ bias,
    void* __restrict__ outp, int Nout)
{
  __shared__ bf16 Asm[128*32];
  __shared__ bf16 Bsm[128*32];
  const int t = threadIdx.x;
  const int w = t>>6, L = t&63;
  const int m0 = blockIdx.x*128, n0 = blockIdx.y*128;
  const int g = blockIdx.z;
  const int wm = w>>1, wn = w&1;
  const int srow = t>>1;
  const int scol = (t&1)*16;
  const int Ktot = K1 + K2;

  f32x4 acc[4][4];
  #pragma unroll
  for (int i=0;i<4;i++)
    #pragma unroll
    for (int j=0;j<4;j++) acc[i][j] = (f32x4){0.f,0.f,0.f,0.f};

  const bf16* Brow = Bw + ((size_t)(g*ngroup + n0 + srow))*ldb;

  for (int k0=0; k0<Ktot; k0+=32){
    short8 a0,a1,b0,b1;
    if (k0 < K1){
      const bf16* ap = A1 + (size_t)(m0+srow)*lda1 + k0 + scol;
      a0 = *(const short8*)ap; a1 = *(const short8*)(ap+8);
    } else {
      const bf16* ap = A2 + (size_t)(m0+srow)*lda2 + (k0-K1) + g*a2_gstride + scol;
      a0 = *(const short8*)ap; a1 = *(const short8*)(ap+8);
    }
    {
      const bf16* bp = Brow + k0 + scol;
      b0 = *(const short8*)bp; b1 = *(const short8*)(bp+8);
    }
    __syncthreads();
    *(short8*)&Asm[srow*32+scol]   = a0; *(short8*)&Asm[srow*32+scol+8] = a1;
    *(short8*)&Bsm[srow*32+scol]   = b0; *(short8*)&Bsm[srow*32+scol+8] = b1;
    __syncthreads();
    short8 af[4], bfr[4];
    #pragma unroll
    for (int f=0;f<4;f++){
      af[f]  = *(const short8*)&Asm[(wm*64 + f*16 + (L&15))*32 + (L>>4)*8];
      bfr[f] = *(const short8*)&Bsm[(wn*64 + f*16 + (L&15))*32 + (L>>4)*8];
    }
    #pragma unroll
    for (int i=0;i<4;i++)
      #pragma unroll
      for (int j=0;j<4;j++)
        acc[i][j] = __builtin_amdgcn_mfma_f32_16x16x32_bf16(af[i], bfr[j], acc[i][j], 0,0,0);
  }

  #pragma unroll
  for (int i=0;i<4;i++){
    #pragma unroll
    for (int j=0;j<4;j++){
      #pragma unroll
      for (int r=0;r<4;r++){
        int m = m0 + wm*64 + i*16 + (L>>4)*4 + r;
        int n = n0 + wn*64 + j*16 + (L&15);
        float val = acc[i][j][r];
        if (MODE==0){
          if (n < Nout){
            val += bias[n];
            float ge = 0.5f*val*(1.f + erff(val*0.70710678f));
            ((bf16*)outp)[(size_t)m*Nout + n] = __float2bfloat16(ge);
          }
        } else if (MODE==1){
          val += bias[g*768 + n];
          int b_ = m>>11, s_ = m&2047, h_ = n>>6, hd = n&63;
          ((float*)outp)[((((size_t)g*B_ + b_)*H_ + h_)*S_ + s_)*HD_ + hd] = val;
        } else {
          ((float*)outp)[(size_t)m*Nout + n] = val;
        }
      }
    }
  }
}

// ---------------- per-head LN (+ k normalization) -> bf16 ----------------
__global__ __launch_bounds__(256) void headln_kernel(const float* __restrict__ kvqf,
    bf16* __restrict__ kvqb,
    const float* __restrict__ lnk_g, const float* __restrict__ lnk_b,
    const float* __restrict__ lnv_g, const float* __restrict__ lnv_b,
    const float* __restrict__ lnq_g, const float* __restrict__ lnq_b){
  int wid = threadIdx.x>>6, lane = threadIdx.x&63;
  size_t r = (size_t)blockIdx.x*4 + wid;
  const float* p = kvqf + r*HD_;
  int proj = (int)(r / ((size_t)B_*H_*S_));
  const float* gp; const float* bp;
  if (proj==0){ gp=lnk_g; bp=lnk_b; } else if (proj==1){ gp=lnv_g; bp=lnv_b; } else { gp=lnq_g; bp=lnq_b; }
  float v = p[lane];
  float mean = wave_reduce_sum(v) * (1.f/64.f);
  float d = v - mean;
  float var = wave_reduce_sum(d*d) * (1.f/64.f);
  float y = d * rsqrtf(var + 1e-5f) * gp[lane] + bp[lane];
  if (proj==0){
    float n2 = wave_reduce_sum(y*y);
    y = y / (sqrtf(n2) + 1e-6f);
  }
  kvqb[r*HD_ + lane] = __float2bfloat16(y);
}

// ---------------- chunk prep: triangular solve + per-chunk GEMM factors ----------------
// Per chunk (C=64): G = Kn Kn^T; solve (I + beta*trilS(G)) X = [V | Kn]  (X = [WV | WKn]);
// AcT[j][k] = I - beta * sum_t Kn[t][j] WKn[t][k]  (split hi/lo bf16)
// Bc[d][j]  = lr  * sum_t WV[t][d]  Kn[t][j]       (fp32)
// Atil[t][i]= (i<t) ? Q[t].Kn[i] : 0               (bf16)
__global__ __launch_bounds__(256) void prep_kernel(
    const bf16* __restrict__ kvqb, const float* __restrict__ lr_scale,
    bf16* __restrict__ WKn, float* __restrict__ WVf,
    bf16* __restrict__ AcThi, bf16* __restrict__ AcTlo,
    float* __restrict__ Bcg, bf16* __restrict__ Atil)
{
  __shared__ __align__(16) char  sKn[8192];   // bf16 [64][64] swizzled
  __shared__ __align__(16) float sG[4096];    // fp32 [i][j]; later aliased by sKnT/sWKnT
  __shared__ __align__(16) float sX[8192];    // fp32 [t][128]; later first 8KB = sQ
  __shared__ __align__(16) char  sWVT[8192];  // bf16 [d][t] swizzled
  char* sKnT  = (char*)sG;
  char* sWKnT = ((char*)sG) + 8192;
  char* sQ    = (char*)sX;

  const int c = blockIdx.x, bh = blockIdx.y;
  const int h = bh % H_;
  const int t = threadIdx.x, w = t>>6, L = t&63;
  const size_t PS = (size_t)B_*H_*S_*HD_;
  const size_t base_k = (size_t)bh*S_*HD_ + (size_t)c*CH*HD_;
  const size_t base_q = 2*PS + base_k;
  const float lr = 0.2f/(1.f + __expf(-lr_scale[h]));
  const float beta = 1.f + lr;
  const size_t cb = ((size_t)bh*NCH + c)*4096;

  // load Kn tile into swizzled LDS
  {
    int r = t>>2, c0 = (t&3)*16;
    const short8* gp = (const short8*)(kvqb + base_k + r*64 + c0);
    short8 v0 = gp[0], v1 = gp[1];
    *(short8*)(sKn + ((r*128 + c0*2) ^ ((r&7)<<4)))     = v0;
    *(short8*)(sKn + ((r*128 + (c0+8)*2) ^ ((r&7)<<4))) = v1;
  }
  __syncthreads();
  // G = Kn Kn^T
  {
    short8 ka[2], kb[4][2];
    #pragma unroll
    for (int kk=0;kk<2;kk++) ka[kk] = lfrag(sKn, 16*w + (L&15), kk*32 + (L>>4)*8);
    #pragma unroll
    for (int nt=0;nt<4;nt++)
      #pragma unroll
      for (int kk=0;kk<2;kk++) kb[nt][kk] = lfrag(sKn, 16*nt + (L&15), kk*32 + (L>>4)*8);
    f32x4 g[4];
    #pragma unroll
    for (int nt=0;nt<4;nt++) g[nt] = (f32x4){0.f,0.f,0.f,0.f};
    #pragma unroll
    for (int nt=0;nt<4;nt++)
      #pragma unroll
      for (int kk=0;kk<2;kk++)
        g[nt] = __builtin_amdgcn_mfma_f32_16x16x32_bf16(ka[kk], kb[nt][kk], g[nt], 0,0,0);
    #pragma unroll
    for (int nt=0;nt<4;nt++)
      #pragma unroll
      for (int r=0;r<4;r++)
        sG[(16*w + (L>>4)*4 + r)*64 + 16*nt + (L&15)] = g[nt][r];
  }
  __syncthreads();
  // forward substitution: wave w owns cols [32w,32w+32) of X (cols 0..63 = V, 64..127 = Kn)
  // row per lane: lane L owns row L. Wave-synchronous (no cross-wave deps).
  {
    float rhs[32], acc[32];
    #pragma unroll
    for (int i=0;i<32;i++) acc[i]=0.f;
    size_t rbase = (w<2) ? (PS + base_k + (size_t)L*64 + 32*w)
                         : (base_k + (size_t)L*64 + 32*(w-2));
    const short8* rp = (const short8*)(kvqb + rbase);
    #pragma unroll
    for (int i8=0;i8<4;i8++){ short8 rv = rp[i8];
      #pragma unroll
      for (int e=0;e<8;e++) rhs[i8*8+e] = us2f((unsigned short)rv[e]); }
    for (int step=0; step<64; ++step){
      if (L == step){
        float* xr = &sX[step*128 + 32*w];
        #pragma unroll
        for (int i=0;i<32;i++) xr[i] = rhs[i] - beta*acc[i];
      }
      __builtin_amdgcn_wave_barrier();
      float gg = sG[step*64 + L];
      const float4* xr4 = (const float4*)&sX[step*128 + 32*w];
      if (L > step){
        #pragma unroll
        for (int i4=0;i4<8;i4++){ float4 xv = xr4[i4];
          acc[i4*4+0] += gg*xv.x; acc[i4*4+1] += gg*xv.y;
          acc[i4*4+2] += gg*xv.z; acc[i4*4+3] += gg*xv.w; }
      }
      __builtin_amdgcn_wave_barrier();
    }
  }
  __syncthreads();
  // global WKn/WVf + transposes (into sG region + sWVT)
  {
    #pragma unroll
    for (int ii=0; ii<16; ii++){
      int i = t + ii*256;
      int r = i>>6, cc = i&63;
      WKn[cb + i] = __float2bfloat16(sX[r*128 + 64 + cc]);
      WVf[cb + i] = sX[r*128 + cc];
    }
    int j = t&63, t0 = (t>>6)*16;
    unsigned short knv[16]; float wkv[16], wvv[16];
    #pragma unroll
    for (int i=0;i<16;i++){
      knv[i] = *(unsigned short*)(sKn + (((t0+i)*128 + j*2) ^ (((t0+i)&7)<<4)));
      wkv[i] = sX[(t0+i)*128 + 64 + j];
      wvv[i] = sX[(t0+i)*128 + j];
    }
    #pragma unroll
    for (int i=0;i<16;i++){
      int off = ((j*128 + (t0+i)*2) ^ ((j&7)<<4));
      *(unsigned short*)(sKnT + off)  = knv[i];
      *(unsigned short*)(sWKnT + off) = f2us(wkv[i]);
      *(unsigned short*)(sWVT + off)  = f2us(wvv[i]);
    }
  }
  __syncthreads();
  // load Q tile into sQ (overwrites sX[0:8KB])
  {
    int r = t>>2, c0 = (t&3)*16;
    const short8* gp = (const short8*)(kvqb + base_q + r*64 + c0);
    short8 v0 = gp[0], v1 = gp[1];
    *(short8*)(sQ + ((r*128 + c0*2) ^ ((r&7)<<4)))     = v0;
    *(short8*)(sQ + ((r*128 + (c0+8)*2) ^ ((r&7)<<4))) = v1;
  }
  __syncthreads();
  // three 64x64x64 GEMMs
  {
    short8 a1[2], a2[2], a3[2], b1[4][2], b2[4][2], b3[4][2];
    #pragma unroll
    for (int kk=0;kk<2;kk++){
      a1[kk] = lfrag(sKnT, 16*w + (L&15), kk*32 + (L>>4)*8);
      a2[kk] = lfrag(sWVT, 16*w + (L&15), kk*32 + (L>>4)*8);
      a3[kk] = lfrag(sQ,   16*w + (L&15), kk*32 + (L>>4)*8);
    }
    #pragma unroll
    for (int nt=0;nt<4;nt++)
      #pragma unroll
      for (int kk=0;kk<2;kk++){
        b1[nt][kk] = lfrag(sWKnT, 16*nt + (L&15), kk*32 + (L>>4)*8);
        b2[nt][kk] = lfrag(sKnT,  16*nt + (L&15), kk*32 + (L>>4)*8);
        b3[nt][kk] = lfrag(sKn,   16*nt + (L&15), kk*32 + (L>>4)*8);
      }
    f32x4 q1[4], q2[4], q3[4];
    #pragma unroll
    for (int nt=0;nt<4;nt++){ q1[nt]=(f32x4){0,0,0,0}; q2[nt]=(f32x4){0,0,0,0}; q3[nt]=(f32x4){0,0,0,0}; }
    #pragma unroll
    for (int nt=0;nt<4;nt++)
      #pragma unroll
      for (int kk=0;kk<2;kk++){
        q1[nt] = __builtin_amdgcn_mfma_f32_16x16x32_bf16(a1[kk], b1[nt][kk], q1[nt], 0,0,0);
        q2[nt] = __builtin_amdgcn_mfma_f32_16x16x32_bf16(a2[kk], b2[nt][kk], q2[nt], 0,0,0);
        q3[nt] = __builtin_amdgcn_mfma_f32_16x16x32_bf16(a3[kk], b3[nt][kk], q3[nt], 0,0,0);
      }
    #pragma unroll
    for (int nt=0;nt<4;nt++)
      #pragma unroll
      for (int r=0;r<4;r++){
        int mrow = 16*w + (L>>4)*4 + r;
        int ncol = 16*nt + (L&15);
        size_t o = cb + (size_t)mrow*64 + ncol;
        float av = ((mrow==ncol)?1.f:0.f) - beta*q1[nt][r];
        bf16 hi = __float2bfloat16(av);
        AcThi[o] = hi;
        AcTlo[o] = __float2bfloat16(av - bf2f(hi));
        Bcg[o]   = lr*q2[nt][r];
        Atil[o]  = __float2bfloat16((ncol < mrow)? q3[nt][r] : 0.f);
      }
  }
}

// ---------------- sequential chunk recurrence: M <- M*Ac + Bc (48 blocks) ----------------
__global__ __launch_bounds__(256) void seq_kernel(
    const bf16* __restrict__ AcThi, const bf16* __restrict__ AcTlo,
    const float* __restrict__ Bcg,
    bf16* __restrict__ Mpref, float* __restrict__ Mout)
{
  __shared__ __align__(16) char sM[4][2][2048];  // [wave][hi/lo][16x64 bf16 swizzled]
  const int bh = blockIdx.x;
  const int t = threadIdx.x, w = t>>6, L = t&63;
  char* mhi = sM[w][0]; char* mlo = sM[w][1];
  const size_t cbase = (size_t)bh*NCH*4096;

  { float4 z = {0.f,0.f,0.f,0.f};
    #pragma unroll
    for (int i=0;i<2;i++){ ((float4*)mhi)[L + 64*i] = z; ((float4*)mlo)[L + 64*i] = z; } }
  { short8 z = {0,0,0,0,0,0,0,0};
    #pragma unroll
    for (int i=0;i<2;i++) ((short8*)(Mpref + cbase))[t + 256*i] = z; }

  short8 Xbh[4][2], Xbl[4][2]; float Xbc[4][4];
  short8 Ybh[4][2], Ybl[4][2]; float Ybc[4][4];

  auto loadf = [&](short8 (&fbh)[4][2], short8 (&fbl)[4][2], float (&fbc)[4][4], int c){
    size_t cb = cbase + (size_t)c*4096;
    #pragma unroll
    for (int nt=0;nt<4;nt++){
      #pragma unroll
      for (int kk=0;kk<2;kk++){
        size_t o = cb + (size_t)(16*nt + (L&15))*64 + kk*32 + (L>>4)*8;
        fbh[nt][kk] = *(const short8*)(AcThi + o);
        fbl[nt][kk] = *(const short8*)(AcTlo + o);
      }
      #pragma unroll
      for (int r=0;r<4;r++)
        fbc[nt][r] = Bcg[cb + (size_t)(16*w + (L>>4)*4 + r)*64 + nt*16 + (L&15)];
    }
  };
  auto compute = [&](short8 (&fbh)[4][2], short8 (&fbl)[4][2], float (&fbc)[4][4], int c){
    short8 ah[2], al[2];
    #pragma unroll
    for (int kk=0;kk<2;kk++){
      ah[kk] = lfrag(mhi, L&15, kk*32 + (L>>4)*8);
      al[kk] = lfrag(mlo, L&15, kk*32 + (L>>4)*8);
    }
    #pragma unroll
    for (int nt=0;nt<4;nt++){
      f32x4 acc = { fbc[nt][0], fbc[nt][1], fbc[nt][2], fbc[nt][3] };
      acc = __builtin_amdgcn_mfma_f32_16x16x32_bf16(ah[0], fbh[nt][0], acc, 0,0,0);
      acc = __builtin_amdgcn_mfma_f32_16x16x32_bf16(ah[1], fbh[nt][1], acc, 0,0,0);
      acc = __builtin_amdgcn_mfma_f32_16x16x32_bf16(ah[0], fbl[nt][0], acc, 0,0,0);
      acc = __builtin_amdgcn_mfma_f32_16x16x32_bf16(ah[1], fbl[nt][1], acc, 0,0,0);
      acc = __builtin_amdgcn_mfma_f32_16x16x32_bf16(al[0], fbh[nt][0], acc, 0,0,0);
      acc = __builtin_amdgcn_mfma_f32_16x16x32_bf16(al[1], fbh[nt][1], acc, 0,0,0);
      #pragma unroll
      for (int r=0;r<4;r++){
        float f = acc[r];
        bf16 hi = __float2bfloat16(f);
        int lrow = (L>>4)*4 + r, col = nt*16 + (L&15);
        int off = ((lrow*128 + col*2) ^ ((lrow&7)<<4));
        *(bf16*)(mhi + off) = hi;
        *(bf16*)(mlo + off) = __float2bfloat16(f - bf2f(hi));
        if (c < NCH-1)
          Mpref[cbase + (size_t)(c+1)*4096 + (size_t)(16*w + lrow)*64 + col] = hi;
        else
          Mout[((size_t)bh*64 + 16*w + lrow)*64 + col] = f;
      }
    }
  };

  loadf(Xbh,Xbl,Xbc,0);
  for (int c=0;c<NCH;c+=2){
    loadf(Ybh,Ybl,Ybc,c+1);
    compute(Xbh,Xbl,Xbc,c);
    if (c+2 < NCH) loadf(Xbh,Xbl,Xbc,c+2);
    compute(Ybh,Ybl,Ybc,c+1);
  }
}

// ---------------- parallel output phase ----------------
// out = Q M0^T + Atil * U,  U = lr*WV - beta*(WKn M0^T)
__global__ __launch_bounds__(256) void outphase_kernel(
    const bf16* __restrict__ kvqb, const bf16* __restrict__ Mpref,
    const bf16* __restrict__ WKn, const float* __restrict__ WVf,
    const bf16* __restrict__ Atil, const float* __restrict__ lr_scale,
    bf16* __restrict__ attn)
{
  __shared__ __align__(16) char sUT[8192];  // bf16 [d][i] swizzled
  const int c = blockIdx.x, bh = blockIdx.y;
  const int b = bh / H_, h = bh % H_;
  const int t = threadIdx.x, w = t>>6, L = t&63;
  const size_t PS = (size_t)B_*H_*S_*HD_;
  const size_t cb = ((size_t)bh*NCH + c)*4096;
  const size_t base_q = 2*PS + (size_t)bh*S_*HD_ + (size_t)c*CH*HD_;
  const float lr = 0.2f/(1.f + __expf(-lr_scale[h]));
  const float beta = 1.f + lr;

  short8 mb[4][2], qa[2], wa[2];
  #pragma unroll
  for (int kk=0;kk<2;kk++){
    qa[kk] = *(const short8*)(kvqb + base_q + (size_t)(16*w + (L&15))*64 + kk*32 + (L>>4)*8);
    wa[kk] = *(const short8*)(WKn + cb + (size_t)(16*w + (L&15))*64 + kk*32 + (L>>4)*8);
  }
  #pragma unroll
  for (int nt=0;nt<4;nt++)
    #pragma unroll
    for (int kk=0;kk<2;kk++)
      mb[nt][kk] = *(const short8*)(Mpref + cb + (size_t)(16*nt + (L&15))*64 + kk*32 + (L>>4)*8);
  f32x4 aout[4], ap[4];
  #pragma unroll
  for (int nt=0;nt<4;nt++){ aout[nt]=(f32x4){0,0,0,0}; ap[nt]=(f32x4){0,0,0,0}; }
  #pragma unroll
  for (int nt=0;nt<4;nt++)
    #pragma unroll
    for (int kk=0;kk<2;kk++){
      aout[nt] = __builtin_amdgcn_mfma_f32_16x16x32_bf16(qa[kk], mb[nt][kk], aout[nt], 0,0,0);
      ap[nt]   = __builtin_amdgcn_mfma_f32_16x16x32_bf16(wa[kk], mb[nt][kk], ap[nt],   0,0,0);
    }
  #pragma unroll
  for (int nt=0;nt<4;nt++){
    unsigned short us[4];
    #pragma unroll
    for (int r=0;r<4;r++){
      float wv = WVf[cb + (size_t)(16*w + (L>>4)*4 + r)*64 + nt*16 + (L&15)];
      us[r] = f2us(lr*wv - beta*ap[nt][r]);
    }
    int d = nt*16 + (L&15);
    int i0 = 16*w + (L>>4)*4;
    s16x4 pk = { (short)us[0], (short)us[1], (short)us[2], (short)us[3] };
    *(s16x4*)(sUT + ((d*128 + i0*2) ^ ((d&7)<<4))) = pk;
  }
  __syncthreads();
  short8 ta[2], ub[4][2];
  #pragma unroll
  for (int kk=0;kk<2;kk++)
    ta[kk] = *(const short8*)(Atil + cb + (size_t)(16*w + (L&15))*64 + kk*32 + (L>>4)*8);
  #pragma unroll
  for (int nt=0;nt<4;nt++)
    #pragma unroll
    for (int kk=0;kk<2;kk++)
      ub[nt][kk] = lfrag(sUT, 16*nt + (L&15), kk*32 + (L>>4)*8);
  #pragma unroll
  for (int nt=0;nt<4;nt++)
    #pragma unroll
    for (int kk=0;kk<2;kk++)
      aout[nt] = __builtin_amdgcn_mfma_f32_16x16x32_bf16(ta[kk], ub[nt][kk], aout[nt], 0,0,0);
  #pragma unroll
  for (int nt=0;nt<4;nt++)
    #pragma unroll
    for (int r=0;r<4;r++)
      attn[((size_t)b*S_ + (size_t)c*CH + 16*w + (L>>4)*4 + r)*P_ + h*HD_ + nt*16 + (L&15)]
        = __float2bfloat16(aout[nt][r]);
}

// ---------------- final gate*proj combine ----------------
__global__ __launch_bounds__(256) void combine_kernel(const float* __restrict__ G1, const float* __restrict__ G2,
                                                      const float* __restrict__ bg, float* __restrict__ out){
  size_t i = (size_t)blockIdx.x*256 + threadIdx.x;
  if (i >= (size_t)M_*D_/4) return;
  float4 a = ((const float4*)G1)[i];
  float4 c = ((const float4*)G2)[i];
  int n = (int)((i*4) % D_);
  float4 r;
  r.x = a.x / (1.f + __expf(-(c.x + bg[n+0])));
  r.y = a.y / (1.f + __expf(-(c.y + bg[n+1])));
  r.z = a.z / (1.f + __expf(-(c.z + bg[n+2])));
  r.w = a.w / (1.f + __expf(-(c.w + bg[n+3])));
  ((float4*)out)[i] = r;
}

extern "C" void kernel_launch(void* const* d_in, const int* in_sizes, int n_in,
                              void* d_out, int out_size, void* d_ws, size_t ws_size,
                              hipStream_t stream)
{
  const float* x     = (const float*)d_in[0];
  const float* ln_g  = (const float*)d_in[1];
  const float* ln_b  = (const float*)d_in[2];
  const float* Wk    = (const float*)d_in[3];
  const float* Wv    = (const float*)d_in[4];
  const float* Wq    = (const float*)d_in[5];
  const float* km_w1 = (const float*)d_in[6];  const float* km_b1 = (const float*)d_in[7];
  const float* km_w2 = (const float*)d_in[8];  const float* km_b2 = (const float*)d_in[9];
  const float* vm_w1 = (const float*)d_in[10]; const float* vm_b1 = (const float*)d_in[11];
  const float* vm_w2 = (const float*)d_in[12]; const float* vm_b2 = (const float*)d_in[13];
  const float* qm_w1 = (const float*)d_in[14]; const float* qm_b1 = (const float*)d_in[15];
  const float* qm_w2 = (const float*)d_in[16]; const float* qm_b2 = (const float*)d_in[17];
  const float* lnk_g = (const float*)d_in[18]; const float* lnk_b = (const float*)d_in[19];
  const float* lnv_g = (const float*)d_in[20]; const float* lnv_b = (const float*)d_in[21];
  const float* lnq_g = (const float*)d_in[22]; const float* lnq_b = (const float*)d_in[23];
  const float* Wo    = (const float*)d_in[24];
  const float* lr_sc = (const float*)d_in[25];
  const float* Wg    = (const float*)d_in[26];
  const float* bg    = (const float*)d_in[27];

  char* ws = (char*)d_ws;
  size_t o = 0;
  bf16* xnb   = (bf16*)(ws + o); o += (size_t)M_*D_*2;          // 12.58 MB
  bf16* xb    = (bf16*)(ws + o); o += (size_t)M_*D_*2;          // 12.58 MB
  bf16* Hb    = (bf16*)(ws + o); o += (size_t)M_*576*2;         // 9.44 MB
  float* kvqf = (float*)(ws + o); size_t o_re = o; o += (size_t)3*M_*P_*4; // 75.5 MB (reused)
  bf16* kvqb  = (bf16*)(ws + o); o += (size_t)3*M_*P_*2;        // 37.75 MB
  bf16* attn  = (bf16*)(ws + o); o += (size_t)M_*P_*2;          // 12.58 MB
  bf16* Mpref = (bf16*)(ws + o); o += (size_t)BH*NCH*4096*2;    // 12.58 MB
  bf16* WKn   = (bf16*)(ws + o); o += (size_t)BH*NCH*4096*2;    // 12.58 MB
  bf16* Atil  = (bf16*)(ws + o); o += (size_t)BH*NCH*4096*2;    // 12.58 MB
  bf16* Whb   = (bf16*)(ws + o); o += (size_t)640*768*2;
  bf16* Wkvqb = (bf16*)(ws + o); o += (size_t)2304*960*2;
  bf16* Wob   = (bf16*)(ws + o); o += (size_t)768*768*2;
  bf16* Wgb   = (bf16*)(ws + o); o += (size_t)768*768*2;
  float* biasb= (float*)(ws + o); o += 2880*4;
  // overlay the dead kvqf region: prep outputs, then final-GEMM outputs
  bf16* AcThi = (bf16*)(ws + o_re);
  bf16* AcTlo = (bf16*)(ws + o_re + 12582912);
  float* Bcg  = (float*)(ws + o_re + 25165824);
  float* WVf  = (float*)(ws + o_re + 50331648);
  float* G1   = (float*)(ws + o_re);
  float* G2   = (float*)(ws + o_re + 25165824);

  float* outF = (float*)d_out;
  float* Mout = outF + (size_t)M_*D_;

  pack_wh_kernel  <<<1920, 256, 0, stream>>>(km_w1, vm_w1, qm_w1, Whb);
  pack_wkvq_kernel<<<8640, 256, 0, stream>>>(Wk, Wv, Wq, km_w2, vm_w2, qm_w2, Wkvqb);
  pack_cast_kernel<<<2304, 256, 0, stream>>>(Wo, Wob, 768*768);
  pack_cast_kernel<<<2304, 256, 0, stream>>>(Wg, Wgb, 768*768);
  pack_bias_kernel<<<12, 256, 0, stream>>>(km_b1, vm_b1, qm_b1, km_b2, vm_b2, qm_b2, biasb);

  ln_in_kernel<<<M_, 256, 0, stream>>>(x, ln_g, ln_b, xnb, xb);

  gemm_kernel<0><<<dim3(64,5,1), 256, 0, stream>>>(xnb, 768, 768, nullptr, 0, 0, 0,
                                                   Whb, 768, 640, biasb, Hb, 576);
  gemm_kernel<1><<<dim3(64,6,3), 256, 0, stream>>>(xnb, 768, 768, Hb, 576, 192, 192,
                                                   Wkvqb, 960, 768, biasb + 576, kvqf, 768);

  headln_kernel<<<73728, 256, 0, stream>>>(kvqf, kvqb, lnk_g, lnk_b, lnv_g, lnv_b, lnq_g, lnq_b);

  prep_kernel<<<dim3(NCH, BH), 256, 0, stream>>>(kvqb, lr_sc, WKn, WVf, AcThi, AcTlo, Bcg, Atil);
  seq_kernel<<<BH, 256, 0, stream>>>(AcThi, AcTlo, Bcg, Mpref, Mout);
  outphase_kernel<<<dim3(NCH, BH), 256, 0, stream>>>(kvqb, Mpref, WKn, WVf, Atil, lr_sc, attn);

  gemm_kernel<2><<<dim3(64,6,1), 256, 0, stream>>>(attn, 768, 768, nullptr, 0, 0, 0,
                                                   Wob, 768, 768, nullptr, G1, 768);
  gemm_kernel<2><<<dim3(64,6,1), 256, 0, stream>>>(xb, 768, 768, nullptr, 0, 0, 0,
                                                   Wgb, 768, 768, nullptr, G2, 768);

  combine_kernel<<<6144, 256, 0, stream>>>(G1, G2, bg, outF);
}

// Round 3
// 402.157 us; speedup vs baseline: 5.3151x; 1.0894x over previous
//
#include <hip/hip_runtime.h>
#include <hip/hip_bf16.h>
#include <math.h>

#define B_ 4
#define S_ 2048
#define D_ 768
#define H_ 12
#define HD_ 64
#define P_ 768
#define M_ (B_*S_)   // 8192
#define NCH 32       // chunks per sequence
#define CH 64        // chunk length
#define BH (B_*H_)   // 48

typedef __hip_bfloat16 bf16;
typedef __attribute__((ext_vector_type(8))) short short8;
typedef __attribute__((ext_vector_type(4))) short s16x4;
typedef __attribute__((ext_vector_type(4))) float f32x4;

__device__ __forceinline__ float wave_reduce_sum(float v){
  #pragma unroll
  for (int off=32; off>0; off>>=1) v += __shfl_xor(v, off, 64);
  return v;
}
__device__ __forceinline__ float bf2f(bf16 h){ return __bfloat162float(h); }
__device__ __forceinline__ float us2f(unsigned short u){
  union{unsigned int i; float f;} z; z.i = ((unsigned int)u)<<16; return z.f;
}
// swizzled LDS [64][64] bf16 tiles (128B rows): byte ^= (row&7)<<4
__device__ __forceinline__ int adr(int row, int col){ return (row*128 + col*2) ^ ((row&7)<<4); }
__device__ __forceinline__ void stb(char* b, int row, int col, float v){
  *(bf16*)(b + adr(row,col)) = __float2bfloat16(v);
}
__device__ __forceinline__ float ldb(const char* b, int row, int col){
  return us2f(*(const unsigned short*)(b + adr(row,col)));
}
__device__ __forceinline__ short8 lfrag(const char* base, int row, int col){
  return *(const short8*)(base + ((row*128 + col*2) ^ ((row&7)<<4)));
}

// ---------------- weight packing ----------------
__global__ __launch_bounds__(256) void pack_wh_kernel(const float* __restrict__ km, const float* __restrict__ vm,
                                                      const float* __restrict__ qm, bf16* __restrict__ out){
  int i = blockIdx.x*256 + threadIdx.x;
  if (i >= 640*768) return;
  int r = i/768, c = i%768;
  float v = 0.f;
  if (r < 192) v = km[r*768+c];
  else if (r < 384) v = vm[(r-192)*768+c];
  else if (r < 576) v = qm[(r-384)*768+c];
  out[i] = __float2bfloat16(v);
}

__global__ __launch_bounds__(256) void pack_wkvq_kernel(const float* __restrict__ Wk,const float* __restrict__ Wv,
                                                        const float* __restrict__ Wq,const float* __restrict__ k2,
                                                        const float* __restrict__ v2,const float* __restrict__ q2,
                                                        bf16* __restrict__ out){
  int i = blockIdx.x*256 + threadIdx.x;
  if (i >= 2304*960) return;
  int r = i/960, c = i%960;
  int p = r/768, rr = r%768;
  const float* W  = (p==0)?Wk:(p==1)?Wv:Wq;
  const float* w2 = (p==0)?k2:(p==1)?v2:q2;
  float v = (c < 768) ? W[(size_t)rr*768+c] : 0.1f*w2[(size_t)rr*192 + (c-768)];
  out[i] = __float2bfloat16(v);
}

__global__ __launch_bounds__(256) void pack_cast_kernel(const float* __restrict__ src, bf16* __restrict__ dst, int n){
  int i = blockIdx.x*256 + threadIdx.x;
  if (i < n) dst[i] = __float2bfloat16(src[i]);
}

__global__ __launch_bounds__(256) void pack_bias_kernel(const float* __restrict__ kb1,const float* __restrict__ vb1,
                                                        const float* __restrict__ qb1,const float* __restrict__ kb2,
                                                        const float* __restrict__ vb2,const float* __restrict__ qb2,
                                                        float* __restrict__ out){
  int i = blockIdx.x*256 + threadIdx.x;
  if (i >= 2880) return;
  if (i < 576){
    out[i] = (i<192)? kb1[i] : (i<384)? vb1[i-192] : qb1[i-384];
  } else {
    int r = i-576; int p = r/768, rr = r%768;
    const float* b2 = (p==0)?kb2:(p==1)?vb2:qb2;
    out[i] = 0.1f*b2[rr];
  }
}

// ---------------- input layernorm ----------------
__global__ __launch_bounds__(256) void ln_in_kernel(const float* __restrict__ x, const float* __restrict__ g,
                                                    const float* __restrict__ bta,
                                                    bf16* __restrict__ xn, bf16* __restrict__ xb){
  int row = blockIdx.x;
  const float* xr = x + (size_t)row*D_;
  int t = threadIdx.x;
  float v0 = xr[t], v1 = xr[t+256], v2 = xr[t+512];
  float s  = v0+v1+v2;
  float sq = v0*v0+v1*v1+v2*v2;
  s = wave_reduce_sum(s); sq = wave_reduce_sum(sq);
  __shared__ float red[8];
  int w = t>>6;
  if ((t&63)==0){ red[w]=s; red[4+w]=sq; }
  __syncthreads();
  s  = red[0]+red[1]+red[2]+red[3];
  sq = red[4]+red[5]+red[6]+red[7];
  float mean = s*(1.f/D_);
  float var  = sq*(1.f/D_) - mean*mean;
  float inv  = rsqrtf(var + 1e-5f);
  bf16* xnr = xn + (size_t)row*D_;
  bf16* xbr = xb + (size_t)row*D_;
  xnr[t]     = __float2bfloat16((v0-mean)*inv*g[t]     + bta[t]);
  xnr[t+256] = __float2bfloat16((v1-mean)*inv*g[t+256] + bta[t+256]);
  xnr[t+512] = __float2bfloat16((v2-mean)*inv*g[t+512] + bta[t+512]);
  xbr[t] = __float2bfloat16(v0); xbr[t+256] = __float2bfloat16(v1); xbr[t+512] = __float2bfloat16(v2);
}

// ---------------- GEMM (bf16 MFMA, 128x128 tile, BK=32, 4 waves 2x2) ----------------
// MODE 0: gelu(val+bias[n]) -> bf16 [M][Nout]
// MODE 1: val+bias[g*768+n] -> bf16 scatter to [g][b][h][s][hd]
// MODE 2: val -> fp32 [M][Nout]
// MODE 3: val * sigmoid(extra[m*768+n]+bias[n]) -> fp32 [M][Nout]
template<int MODE>
__global__ __launch_bounds__(256) void gemm_kernel(
    const bf16* __restrict__ A1, int lda1, int K1,
    const bf16* __restrict__ A2, int lda2, int K2, int a2_gstride,
    const bf16* __restrict__ Bw, int ldb, int ngroup,
    const float* __restrict__ bias, const float* __restrict__ extra,
    void* __restrict__ outp, int Nout)
{
  __shared__ bf16 Asm[128*32];
  __shared__ bf16 Bsm[128*32];
  const int t = threadIdx.x;
  const int w = t>>6, L = t&63;
  const int m0 = blockIdx.x*128, n0 = blockIdx.y*128;
  const int g = blockIdx.z;
  const int wm = w>>1, wn = w&1;
  const int srow = t>>1;
  const int scol = (t&1)*16;
  const int Ktot = K1 + K2;

  f32x4 acc[4][4];
  #pragma unroll
  for (int i=0;i<4;i++)
    #pragma unroll
    for (int j=0;j<4;j++) acc[i][j] = (f32x4){0.f,0.f,0.f,0.f};

  const bf16* Brow = Bw + ((size_t)(g*ngroup + n0 + srow))*ldb;

  for (int k0=0; k0<Ktot; k0+=32){
    short8 a0,a1,b0,b1;
    if (k0 < K1){
      const bf16* ap = A1 + (size_t)(m0+srow)*lda1 + k0 + scol;
      a0 = *(const short8*)ap; a1 = *(const short8*)(ap+8);
    } else {
      const bf16* ap = A2 + (size_t)(m0+srow)*lda2 + (k0-K1) + g*a2_gstride + scol;
      a0 = *(const short8*)ap; a1 = *(const short8*)(ap+8);
    }
    {
      const bf16* bp = Brow + k0 + scol;
      b0 = *(const short8*)bp; b1 = *(const short8*)(bp+8);
    }
    __syncthreads();
    *(short8*)&Asm[srow*32+scol]   = a0; *(short8*)&Asm[srow*32+scol+8] = a1;
    *(short8*)&Bsm[srow*32+scol]   = b0; *(short8*)&Bsm[srow*32+scol+8] = b1;
    __syncthreads();
    short8 af[4], bfr[4];
    #pragma unroll
    for (int f=0;f<4;f++){
      af[f]  = *(const short8*)&Asm[(wm*64 + f*16 + (L&15))*32 + (L>>4)*8];
      bfr[f] = *(const short8*)&Bsm[(wn*64 + f*16 + (L&15))*32 + (L>>4)*8];
    }
    #pragma unroll
    for (int i=0;i<4;i++)
      #pragma unroll
      for (int j=0;j<4;j++)
        acc[i][j] = __builtin_amdgcn_mfma_f32_16x16x32_bf16(af[i], bfr[j], acc[i][j], 0,0,0);
  }

  #pragma unroll
  for (int i=0;i<4;i++){
    #pragma unroll
    for (int j=0;j<4;j++){
      #pragma unroll
      for (int r=0;r<4;r++){
        int m = m0 + wm*64 + i*16 + (L>>4)*4 + r;
        int n = n0 + wn*64 + j*16 + (L&15);
        float val = acc[i][j][r];
        if (MODE==0){
          if (n < Nout){
            val += bias[n];
            float ge = 0.5f*val*(1.f + erff(val*0.70710678f));
            ((bf16*)outp)[(size_t)m*Nout + n] = __float2bfloat16(ge);
          }
        } else if (MODE==1){
          val += bias[g*768 + n];
          int b_ = m>>11, s_ = m&2047, h_ = n>>6, hd = n&63;
          ((bf16*)outp)[((((size_t)g*B_ + b_)*H_ + h_)*S_ + s_)*HD_ + hd] = __float2bfloat16(val);
        } else if (MODE==2){
          ((float*)outp)[(size_t)m*Nout + n] = val;
        } else {
          float g2 = extra[(size_t)m*768 + n] + bias[n];
          float gate = 1.f/(1.f + __expf(-g2));
          ((float*)outp)[(size_t)m*Nout + n] = val * gate;
        }
      }
    }
  }
}

// ---------------- per-head LN (+ k normalization), in-place bf16 ----------------
__global__ __launch_bounds__(256) void headln_kernel(bf16* __restrict__ kvq,
    const float* __restrict__ lnk_g, const float* __restrict__ lnk_b,
    const float* __restrict__ lnv_g, const float* __restrict__ lnv_b,
    const float* __restrict__ lnq_g, const float* __restrict__ lnq_b){
  int wid = threadIdx.x>>6, lane = threadIdx.x&63;
  size_t r = (size_t)blockIdx.x*4 + wid;
  bf16* p = kvq + r*HD_;
  int proj = (int)(r / ((size_t)B_*H_*S_));
  const float* gp; const float* bp;
  if (proj==0){ gp=lnk_g; bp=lnk_b; } else if (proj==1){ gp=lnv_g; bp=lnv_b; } else { gp=lnq_g; bp=lnq_b; }
  float v = bf2f(p[lane]);
  float mean = wave_reduce_sum(v) * (1.f/64.f);
  float d = v - mean;
  float var = wave_reduce_sum(d*d) * (1.f/64.f);
  float y = d * rsqrtf(var + 1e-5f) * gp[lane] + bp[lane];
  if (proj==0){
    float n2 = wave_reduce_sum(y*y);
    y = y / (sqrtf(n2) + 1e-6f);
  }
  p[lane] = __float2bfloat16(y);
}

// ---------------- chunk prep: log-depth triangular inverse + per-chunk GEMM factors ----------------
// T = (I+N)^-1 = (I-N)(I+N^2)(I+N^4)(I+N^8)(I+N^16)(I+N^32), N = beta*trilS(Kn Kn^T)
// WKn = T*Kn, WV = T*V (stored transposed as WVT); AcT = I - beta*Kn^T WKn; Bc = lr*WV^T Kn;
// Atil = strict_lower(Q Kn^T)
__global__ __launch_bounds__(256) void prep_kernel(
    const bf16* __restrict__ kvqb, const float* __restrict__ lr_scale,
    bf16* __restrict__ WKng, bf16* __restrict__ WVTg,
    bf16* __restrict__ AcThi, bf16* __restrict__ AcTlo,
    bf16* __restrict__ Bcb, bf16* __restrict__ Atil)
{
  __shared__ __align__(16) char LA[8192]; // Thi -> WVT
  __shared__ __align__(16) char LB[8192]; // Tlo -> WKnT
  __shared__ __align__(16) char LC[8192]; // P   -> KnT -> Bc bounce
  __shared__ __align__(16) char LD[8192]; // PT  -> VT  -> Atil bounce
  __shared__ __align__(16) char LE[8192]; // AcThi bounce
  __shared__ __align__(16) char LF[8192]; // AcTlo bounce

  const int c = blockIdx.x, bh = blockIdx.y;
  const int h = bh % H_;
  const int t = threadIdx.x, w = t>>6, L = t&63;
  const size_t PS = (size_t)B_*H_*S_*HD_;
  const size_t base_k = (size_t)bh*S_*HD_ + (size_t)c*CH*HD_;
  const float lr = 0.2f/(1.f + __expf(-lr_scale[h]));
  const float beta = 1.f + lr;
  const size_t cb = ((size_t)bh*NCH + c)*4096;
  const bf16* Kg = kvqb + base_k;
  const bf16* Vg = kvqb + PS + base_k;
  const bf16* Qg = kvqb + 2*PS + base_k;

  const int fr = L&15;        // frag load row within tile
  const int fc = (L>>4)*8;    // frag load col base
  const int cmr = (L>>4)*4;   // C row base within tile

  // ---- Phase 0: G = Kn Kn^T (direct-global frags), init N/NT/T
  {
    short8 gA[2], gB[4][2];
    #pragma unroll
    for (int kk=0;kk<2;kk++)
      gA[kk] = *(const short8*)(Kg + (16*w + fr)*64 + kk*32 + fc);
    #pragma unroll
    for (int nt=0;nt<4;nt++)
      #pragma unroll
      for (int kk=0;kk<2;kk++)
        gB[nt][kk] = *(const short8*)(Kg + (16*nt + fr)*64 + kk*32 + fc);
    f32x4 g[4];
    #pragma unroll
    for (int nt=0;nt<4;nt++) g[nt]=(f32x4){0.f,0.f,0.f,0.f};
    #pragma unroll
    for (int nt=0;nt<4;nt++)
      #pragma unroll
      for (int kk=0;kk<2;kk++)
        g[nt] = __builtin_amdgcn_mfma_f32_16x16x32_bf16(gA[kk], gB[nt][kk], g[nt], 0,0,0);
    #pragma unroll
    for (int nt=0;nt<4;nt++)
      #pragma unroll
      for (int r=0;r<4;r++){
        int m = 16*w + cmr + r, n = 16*nt + (L&15);
        float val = beta * g[nt][r];
        float pv  = (m>n)? val : 0.f;       // N[m][n]
        float ptv = (n>m)? val : 0.f;       // N^T[m][n] (G symmetric)
        float tv  = ((m==n)?1.f:0.f) - pv;  // T1 = I - N
        float thi = bf2f(__float2bfloat16(tv));
        stb(LC, m, n, pv);
        stb(LD, m, n, ptv);
        stb(LA, m, n, thi);
        stb(LB, m, n, tv - thi);
      }
  }
  __syncthreads();

  // ---- Doubling stages: s>=1: T += T*N^(2^s); s<=4: square N^(2^s) -> N^(2^(s+1))
  #pragma unroll 1
  for (int s=0; s<6; ++s){
    const bool do_upd = (s>=1), do_sq = (s<=4);
    short8 ahi[2], alo[2], aPT[2], bPT[4][2], bP[4][2];
    f32x4 upd[4], sq[4];
    if (do_upd){
      #pragma unroll
      for (int kk=0;kk<2;kk++){
        ahi[kk] = lfrag(LA, 16*w+fr, kk*32+fc);
        alo[kk] = lfrag(LB, 16*w+fr, kk*32+fc);
      }
      #pragma unroll
      for (int nt=0;nt<4;nt++){
        #pragma unroll
        for (int kk=0;kk<2;kk++)
          bPT[nt][kk] = lfrag(LD, 16*nt+fr, kk*32+fc);
        #pragma unroll
        for (int r=0;r<4;r++){
          int m = 16*w+cmr+r, n = 16*nt+(L&15);
          upd[nt][r] = ldb(LA,m,n) + ldb(LB,m,n);
        }
      }
    }
    if (do_sq){
      #pragma unroll
      for (int kk=0;kk<2;kk++) aPT[kk] = lfrag(LD, 16*w+fr, kk*32+fc);
      #pragma unroll
      for (int nt=0;nt<4;nt++){
        #pragma unroll
        for (int kk=0;kk<2;kk++) bP[nt][kk] = lfrag(LC, 16*nt+fr, kk*32+fc);
        sq[nt] = (f32x4){0.f,0.f,0.f,0.f};
      }
    }
    if (do_upd){
      #pragma unroll
      for (int nt=0;nt<4;nt++)
        #pragma unroll
        for (int kk=0;kk<2;kk++){
          upd[nt] = __builtin_amdgcn_mfma_f32_16x16x32_bf16(ahi[kk], bPT[nt][kk], upd[nt], 0,0,0);
          upd[nt] = __builtin_amdgcn_mfma_f32_16x16x32_bf16(alo[kk], bPT[nt][kk], upd[nt], 0,0,0);
        }
    }
    if (do_sq){
      #pragma unroll
      for (int nt=0;nt<4;nt++)
        #pragma unroll
        for (int kk=0;kk<2;kk++)
          sq[nt] = __builtin_amdgcn_mfma_f32_16x16x32_bf16(aPT[kk], bP[nt][kk], sq[nt], 0,0,0);
    }
    __syncthreads();
    if (do_upd){
      #pragma unroll
      for (int nt=0;nt<4;nt++)
        #pragma unroll
        for (int r=0;r<4;r++){
          int m = 16*w+cmr+r, n = 16*nt+(L&15);
          float tv = upd[nt][r];
          float thi = bf2f(__float2bfloat16(tv));
          stb(LA, m, n, thi);
          stb(LB, m, n, tv - thi);
        }
    }
    if (do_sq){
      #pragma unroll
      for (int nt=0;nt<4;nt++)
        #pragma unroll
        for (int r=0;r<4;r++){
          int m = 16*w+cmr+r, n = 16*nt+(L&15);
          float v = sq[nt][r];          // (N^2p)^T [m][n]
          stb(LD, m, n, v);             // PT_new
          stb(LC, n, m, v);             // P_new
        }
    }
    __syncthreads();
  }

  // ---- Build KnT->LC, VT->LD (P/PT dead)
  {
    int row = t>>2, seg = (t&3)*16;
    unsigned short kv[16], vv[16];
    #pragma unroll
    for (int i=0;i<16;i++){
      kv[i] = *(const unsigned short*)(Kg + (seg+i)*64 + row);
      vv[i] = *(const unsigned short*)(Vg + (seg+i)*64 + row);
    }
    short8 p0,p1,q0,q1v;
    #pragma unroll
    for (int e=0;e<8;e++){ p0[e]=(short)kv[e]; p1[e]=(short)kv[8+e]; q0[e]=(short)vv[e]; q1v[e]=(short)vv[8+e]; }
    *(short8*)(LC + adr(row,seg))   = p0;
    *(short8*)(LC + adr(row,seg+8)) = p1;
    *(short8*)(LD + adr(row,seg))   = q0;
    *(short8*)(LD + adr(row,seg+8)) = q1v;
  }
  __syncthreads();

  // ---- Apply: WVT = VT*T', WKnT = KnT*T'  (C[m=d][n=t] = (T R)[t][d])
  f32x4 xv[4], xk[4];
  {
    short8 aV[2], aK[2], bh_[4][2], bl_[4][2];
    #pragma unroll
    for (int kk=0;kk<2;kk++){
      aV[kk] = lfrag(LD, 16*w+fr, kk*32+fc);
      aK[kk] = lfrag(LC, 16*w+fr, kk*32+fc);
    }
    #pragma unroll
    for (int nt=0;nt<4;nt++){
      #pragma unroll
      for (int kk=0;kk<2;kk++){
        bh_[nt][kk] = lfrag(LA, 16*nt+fr, kk*32+fc);
        bl_[nt][kk] = lfrag(LB, 16*nt+fr, kk*32+fc);
      }
      xv[nt]=(f32x4){0.f,0.f,0.f,0.f}; xk[nt]=(f32x4){0.f,0.f,0.f,0.f};
    }
    #pragma unroll
    for (int nt=0;nt<4;nt++)
      #pragma unroll
      for (int kk=0;kk<2;kk++){
        xv[nt] = __builtin_amdgcn_mfma_f32_16x16x32_bf16(aV[kk], bh_[nt][kk], xv[nt], 0,0,0);
        xv[nt] = __builtin_amdgcn_mfma_f32_16x16x32_bf16(aV[kk], bl_[nt][kk], xv[nt], 0,0,0);
        xk[nt] = __builtin_amdgcn_mfma_f32_16x16x32_bf16(aK[kk], bh_[nt][kk], xk[nt], 0,0,0);
        xk[nt] = __builtin_amdgcn_mfma_f32_16x16x32_bf16(aK[kk], bl_[nt][kk], xk[nt], 0,0,0);
      }
  }
  __syncthreads();
  #pragma unroll
  for (int nt=0;nt<4;nt++)
    #pragma unroll
    for (int r=0;r<4;r++){
      int m = 16*w+cmr+r, n = 16*nt+(L&15);
      stb(LA, m, n, xv[nt][r]);   // WVT[d][t]
      stb(LB, m, n, xk[nt][r]);   // WKnT[j][t]
    }
  __syncthreads();

  // ---- q1 = Kn^T WKn (AcT core), q2 = WV^T Kn (Bc), q3 = Q Kn^T (Atil)
  f32x4 q1[4], q2[4], q3[4];
  {
    short8 aK2[2], aWV[2], aQ[2], bWK[4][2], bK2[4][2], bKg[4][2];
    #pragma unroll
    for (int kk=0;kk<2;kk++){
      aK2[kk] = lfrag(LC, 16*w+fr, kk*32+fc);
      aWV[kk] = lfrag(LA, 16*w+fr, kk*32+fc);
      aQ[kk]  = *(const short8*)(Qg + (16*w+fr)*64 + kk*32 + fc);
    }
    #pragma unroll
    for (int nt=0;nt<4;nt++){
      #pragma unroll
      for (int kk=0;kk<2;kk++){
        bWK[nt][kk] = lfrag(LB, 16*nt+fr, kk*32+fc);
        bK2[nt][kk] = lfrag(LC, 16*nt+fr, kk*32+fc);
        bKg[nt][kk] = *(const short8*)(Kg + (16*nt+fr)*64 + kk*32 + fc);
      }
      q1[nt]=(f32x4){0.f,0.f,0.f,0.f}; q2[nt]=(f32x4){0.f,0.f,0.f,0.f}; q3[nt]=(f32x4){0.f,0.f,0.f,0.f};
    }
    #pragma unroll
    for (int nt=0;nt<4;nt++)
      #pragma unroll
      for (int kk=0;kk<2;kk++){
        q1[nt] = __builtin_amdgcn_mfma_f32_16x16x32_bf16(aK2[kk], bWK[nt][kk], q1[nt], 0,0,0);
        q2[nt] = __builtin_amdgcn_mfma_f32_16x16x32_bf16(aWV[kk], bK2[nt][kk], q2[nt], 0,0,0);
        q3[nt] = __builtin_amdgcn_mfma_f32_16x16x32_bf16(aQ[kk],  bKg[nt][kk], q3[nt], 0,0,0);
      }
  }
  __syncthreads();
  #pragma unroll
  for (int nt=0;nt<4;nt++)
    #pragma unroll
    for (int r=0;r<4;r++){
      int m = 16*w+cmr+r, n = 16*nt+(L&15);
      float av = ((m==n)?1.f:0.f) - beta*q1[nt][r];
      float ahiv = bf2f(__float2bfloat16(av));
      stb(LE, m, n, ahiv);
      stb(LF, m, n, av - ahiv);
      stb(LC, m, n, lr*q2[nt][r]);              // Bc[d][j]
      stb(LD, m, n, (n<m)? q3[nt][r] : 0.f);    // Atil[t][i]
    }
  __syncthreads();

  // ---- coalesced global writes
  {
    int row = t>>2, seg = (t&3)*16;
    size_t go = cb + (size_t)row*64 + seg;
    *(short8*)(AcThi+go)   = *(const short8*)(LE + adr(row,seg));
    *(short8*)(AcThi+go+8) = *(const short8*)(LE + adr(row,seg+8));
    *(short8*)(AcTlo+go)   = *(const short8*)(LF + adr(row,seg));
    *(short8*)(AcTlo+go+8) = *(const short8*)(LF + adr(row,seg+8));
    *(short8*)(Bcb+go)     = *(const short8*)(LC + adr(row,seg));
    *(short8*)(Bcb+go+8)   = *(const short8*)(LC + adr(row,seg+8));
    *(short8*)(Atil+go)    = *(const short8*)(LD + adr(row,seg));
    *(short8*)(Atil+go+8)  = *(const short8*)(LD + adr(row,seg+8));
    *(short8*)(WVTg+go)    = *(const short8*)(LA + adr(row,seg));
    *(short8*)(WVTg+go+8)  = *(const short8*)(LA + adr(row,seg+8));
    unsigned short wk[16];
    #pragma unroll
    for (int i=0;i<16;i++) wk[i] = *(const unsigned short*)(LB + adr(seg+i, row));
    short8 w0, w1;
    #pragma unroll
    for (int e=0;e<8;e++){ w0[e]=(short)wk[e]; w1[e]=(short)wk[8+e]; }
    *(short8*)(WKng+go)   = w0;   // WKn[t][j]
    *(short8*)(WKng+go+8) = w1;
  }
}

// ---------------- sequential chunk recurrence: M <- M*Ac + Bc (48 blocks) ----------------
__global__ __launch_bounds__(256) void seq_kernel(
    const bf16* __restrict__ AcThi, const bf16* __restrict__ AcTlo,
    const bf16* __restrict__ Bcb,
    bf16* __restrict__ Mpref, float* __restrict__ Mout)
{
  __shared__ __align__(16) char sM[4][2][2048];
  const int bh = blockIdx.x;
  const int t = threadIdx.x, w = t>>6, L = t&63;
  char* mhi = sM[w][0]; char* mlo = sM[w][1];
  const size_t cbase = (size_t)bh*NCH*4096;

  { float4 z = {0.f,0.f,0.f,0.f};
    #pragma unroll
    for (int i=0;i<2;i++){ ((float4*)mhi)[L + 64*i] = z; ((float4*)mlo)[L + 64*i] = z; } }
  { short8 z = {0,0,0,0,0,0,0,0};
    #pragma unroll
    for (int i=0;i<2;i++) ((short8*)(Mpref + cbase))[t + 256*i] = z; }

  short8 Xbh[4][2], Xbl[4][2]; float Xbc[4][4];
  short8 Ybh[4][2], Ybl[4][2]; float Ybc[4][4];

  auto loadf = [&](short8 (&fbh)[4][2], short8 (&fbl)[4][2], float (&fbc)[4][4], int c){
    size_t cb = cbase + (size_t)c*4096;
    #pragma unroll
    for (int nt=0;nt<4;nt++){
      #pragma unroll
      for (int kk=0;kk<2;kk++){
        size_t o = cb + (size_t)(16*nt + (L&15))*64 + kk*32 + (L>>4)*8;
        fbh[nt][kk] = *(const short8*)(AcThi + o);
        fbl[nt][kk] = *(const short8*)(AcTlo + o);
      }
      #pragma unroll
      for (int r=0;r<4;r++)
        fbc[nt][r] = us2f(*(const unsigned short*)(Bcb + cb + (size_t)(16*w + (L>>4)*4 + r)*64 + nt*16 + (L&15)));
    }
  };
  auto compute = [&](short8 (&fbh)[4][2], short8 (&fbl)[4][2], float (&fbc)[4][4], int c){
    short8 ah[2], al[2];
    #pragma unroll
    for (int kk=0;kk<2;kk++){
      ah[kk] = lfrag(mhi, L&15, kk*32 + (L>>4)*8);
      al[kk] = lfrag(mlo, L&15, kk*32 + (L>>4)*8);
    }
    #pragma unroll
    for (int nt=0;nt<4;nt++){
      f32x4 acc = { fbc[nt][0], fbc[nt][1], fbc[nt][2], fbc[nt][3] };
      acc = __builtin_amdgcn_mfma_f32_16x16x32_bf16(ah[0], fbh[nt][0], acc, 0,0,0);
      acc = __builtin_amdgcn_mfma_f32_16x16x32_bf16(ah[1], fbh[nt][1], acc, 0,0,0);
      acc = __builtin_amdgcn_mfma_f32_16x16x32_bf16(ah[0], fbl[nt][0], acc, 0,0,0);
      acc = __builtin_amdgcn_mfma_f32_16x16x32_bf16(ah[1], fbl[nt][1], acc, 0,0,0);
      acc = __builtin_amdgcn_mfma_f32_16x16x32_bf16(al[0], fbh[nt][0], acc, 0,0,0);
      acc = __builtin_amdgcn_mfma_f32_16x16x32_bf16(al[1], fbh[nt][1], acc, 0,0,0);
      #pragma unroll
      for (int r=0;r<4;r++){
        float f = acc[r];
        bf16 hi = __float2bfloat16(f);
        int lrow = (L>>4)*4 + r, col = nt*16 + (L&15);
        int off = ((lrow*128 + col*2) ^ ((lrow&7)<<4));
        *(bf16*)(mhi + off) = hi;
        *(bf16*)(mlo + off) = __float2bfloat16(f - bf2f(hi));
        if (c < NCH-1)
          Mpref[cbase + (size_t)(c+1)*4096 + (size_t)(16*w + lrow)*64 + col] = hi;
        else
          Mout[((size_t)bh*64 + 16*w + lrow)*64 + col] = f;
      }
    }
  };

  loadf(Xbh,Xbl,Xbc,0);
  for (int c=0;c<NCH;c+=2){
    loadf(Ybh,Ybl,Ybc,c+1);
    compute(Xbh,Xbl,Xbc,c);
    if (c+2 < NCH) loadf(Xbh,Xbl,Xbc,c+2);
    compute(Ybh,Ybl,Ybc,c+1);
  }
}

// ---------------- parallel output phase ----------------
// out = Q M0^T + Atil * U,  U = lr*WV - beta*(WKn M0^T)
__global__ __launch_bounds__(256) void outphase_kernel(
    const bf16* __restrict__ kvqb, const bf16* __restrict__ Mpref,
    const bf16* __restrict__ WKng, const bf16* __restrict__ WVTb,
    const bf16* __restrict__ Atil, const float* __restrict__ lr_scale,
    bf16* __restrict__ attn)
{
  __shared__ __align__(16) char sUT[8192];
  const int c = blockIdx.x, bh = blockIdx.y;
  const int b = bh / H_, h = bh % H_;
  const int t = threadIdx.x, w = t>>6, L = t&63;
  const size_t PS = (size_t)B_*H_*S_*HD_;
  const size_t cb = ((size_t)bh*NCH + c)*4096;
  const size_t base_q = 2*PS + (size_t)bh*S_*HD_ + (size_t)c*CH*HD_;
  const float lr = 0.2f/(1.f + __expf(-lr_scale[h]));
  const float beta = 1.f + lr;

  short8 mb[4][2], qa[2], wa[2];
  #pragma unroll
  for (int kk=0;kk<2;kk++){
    qa[kk] = *(const short8*)(kvqb + base_q + (size_t)(16*w + (L&15))*64 + kk*32 + (L>>4)*8);
    wa[kk] = *(const short8*)(WKng + cb + (size_t)(16*w + (L&15))*64 + kk*32 + (L>>4)*8);
  }
  #pragma unroll
  for (int nt=0;nt<4;nt++)
    #pragma unroll
    for (int kk=0;kk<2;kk++)
      mb[nt][kk] = *(const short8*)(Mpref + cb + (size_t)(16*nt + (L&15))*64 + kk*32 + (L>>4)*8);
  f32x4 aout[4], ap[4];
  #pragma unroll
  for (int nt=0;nt<4;nt++){ aout[nt]=(f32x4){0.f,0.f,0.f,0.f}; ap[nt]=(f32x4){0.f,0.f,0.f,0.f}; }
  #pragma unroll
  for (int nt=0;nt<4;nt++)
    #pragma unroll
    for (int kk=0;kk<2;kk++){
      aout[nt] = __builtin_amdgcn_mfma_f32_16x16x32_bf16(qa[kk], mb[nt][kk], aout[nt], 0,0,0);
      ap[nt]   = __builtin_amdgcn_mfma_f32_16x16x32_bf16(wa[kk], mb[nt][kk], ap[nt],   0,0,0);
    }
  #pragma unroll
  for (int nt=0;nt<4;nt++){
    unsigned short us[4];
    #pragma unroll
    for (int r=0;r<4;r++){
      float wv = us2f(*(const unsigned short*)(WVTb + cb + (size_t)(nt*16 + (L&15))*64 + 16*w + (L>>4)*4 + r));
      bf16 hb = __float2bfloat16(lr*wv - beta*ap[nt][r]);
      us[r] = *(unsigned short*)&hb;
    }
    int d = nt*16 + (L&15);
    int i0 = 16*w + (L>>4)*4;
    s16x4 pk = { (short)us[0], (short)us[1], (short)us[2], (short)us[3] };
    *(s16x4*)(sUT + ((d*128 + i0*2) ^ ((d&7)<<4))) = pk;
  }
  __syncthreads();
  short8 ta[2], ub[4][2];
  #pragma unroll
  for (int kk=0;kk<2;kk++)
    ta[kk] = *(const short8*)(Atil + cb + (size_t)(16*w + (L&15))*64 + kk*32 + (L>>4)*8);
  #pragma unroll
  for (int nt=0;nt<4;nt++)
    #pragma unroll
    for (int kk=0;kk<2;kk++)
      ub[nt][kk] = lfrag(sUT, 16*nt + (L&15), kk*32 + (L>>4)*8);
  #pragma unroll
  for (int nt=0;nt<4;nt++)
    #pragma unroll
    for (int kk=0;kk<2;kk++)
      aout[nt] = __builtin_amdgcn_mfma_f32_16x16x32_bf16(ta[kk], ub[nt][kk], aout[nt], 0,0,0);
  #pragma unroll
  for (int nt=0;nt<4;nt++)
    #pragma unroll
    for (int r=0;r<4;r++)
      attn[((size_t)b*S_ + (size_t)c*CH + 16*w + (L>>4)*4 + r)*P_ + h*HD_ + nt*16 + (L&15)]
        = __float2bfloat16(aout[nt][r]);
}

extern "C" void kernel_launch(void* const* d_in, const int* in_sizes, int n_in,
                              void* d_out, int out_size, void* d_ws, size_t ws_size,
                              hipStream_t stream)
{
  const float* x     = (const float*)d_in[0];
  const float* ln_g  = (const float*)d_in[1];
  const float* ln_b  = (const float*)d_in[2];
  const float* Wk    = (const float*)d_in[3];
  const float* Wv    = (const float*)d_in[4];
  const float* Wq    = (const float*)d_in[5];
  const float* km_w1 = (const float*)d_in[6];  const float* km_b1 = (const float*)d_in[7];
  const float* km_w2 = (const float*)d_in[8];  const float* km_b2 = (const float*)d_in[9];
  const float* vm_w1 = (const float*)d_in[10]; const float* vm_b1 = (const float*)d_in[11];
  const float* vm_w2 = (const float*)d_in[12]; const float* vm_b2 = (const float*)d_in[13];
  const float* qm_w1 = (const float*)d_in[14]; const float* qm_b1 = (const float*)d_in[15];
  const float* qm_w2 = (const float*)d_in[16]; const float* qm_b2 = (const float*)d_in[17];
  const float* lnk_g = (const float*)d_in[18]; const float* lnk_b = (const float*)d_in[19];
  const float* lnv_g = (const float*)d_in[20]; const float* lnv_b = (const float*)d_in[21];
  const float* lnq_g = (const float*)d_in[22]; const float* lnq_b = (const float*)d_in[23];
  const float* Wo    = (const float*)d_in[24];
  const float* lr_sc = (const float*)d_in[25];
  const float* Wg    = (const float*)d_in[26];
  const float* bg    = (const float*)d_in[27];

  const size_t CHB = (size_t)BH*NCH*4096;  // elements per chunk array

  char* ws = (char*)d_ws;
  size_t o = 0;
  bf16* xnb   = (bf16*)(ws + o); o += (size_t)M_*D_*2;
  bf16* xb    = (bf16*)(ws + o); o += (size_t)M_*D_*2;
  bf16* Hb    = (bf16*)(ws + o); o += (size_t)M_*576*2;
  bf16* kvqb  = (bf16*)(ws + o); o += (size_t)3*M_*P_*2;
  bf16* attn  = (bf16*)(ws + o); o += (size_t)M_*P_*2;
  size_t o_p = o;
  bf16* AcThi = (bf16*)(ws + o); o += CHB*2;
  bf16* AcTlo = (bf16*)(ws + o); o += CHB*2;
  bf16* Bcb   = (bf16*)(ws + o); o += CHB*2;
  bf16* Atil  = (bf16*)(ws + o); o += CHB*2;
  bf16* WVTb  = (bf16*)(ws + o); o += CHB*2;
  bf16* WKng  = (bf16*)(ws + o); o += CHB*2;
  bf16* Mpref = (bf16*)(ws + o); o += CHB*2;
  bf16* Whb   = (bf16*)(ws + o); o += (size_t)640*768*2;
  bf16* Wkvqb = (bf16*)(ws + o); o += (size_t)2304*960*2;
  bf16* Wob   = (bf16*)(ws + o); o += (size_t)768*768*2;
  bf16* Wgb   = (bf16*)(ws + o); o += (size_t)768*768*2;
  float* biasb= (float*)(ws + o); o += 2880*4;
  // G2 overlays AcThi+AcTlo (dead after seq)
  float* G2   = (float*)(ws + o_p);

  float* outF = (float*)d_out;
  float* Mout = outF + (size_t)M_*D_;

  pack_wh_kernel  <<<1920, 256, 0, stream>>>(km_w1, vm_w1, qm_w1, Whb);
  pack_wkvq_kernel<<<8640, 256, 0, stream>>>(Wk, Wv, Wq, km_w2, vm_w2, qm_w2, Wkvqb);
  pack_cast_kernel<<<2304, 256, 0, stream>>>(Wo, Wob, 768*768);
  pack_cast_kernel<<<2304, 256, 0, stream>>>(Wg, Wgb, 768*768);
  pack_bias_kernel<<<12, 256, 0, stream>>>(km_b1, vm_b1, qm_b1, km_b2, vm_b2, qm_b2, biasb);

  ln_in_kernel<<<M_, 256, 0, stream>>>(x, ln_g, ln_b, xnb, xb);

  gemm_kernel<0><<<dim3(64,5,1), 256, 0, stream>>>(xnb, 768, 768, nullptr, 0, 0, 0,
                                                   Whb, 768, 640, biasb, nullptr, Hb, 576);
  gemm_kernel<1><<<dim3(64,6,3), 256, 0, stream>>>(xnb, 768, 768, Hb, 576, 192, 192,
                                                   Wkvqb, 960, 768, biasb + 576, nullptr, kvqb, 768);

  headln_kernel<<<73728, 256, 0, stream>>>(kvqb, lnk_g, lnk_b, lnv_g, lnv_b, lnq_g, lnq_b);

  prep_kernel<<<dim3(NCH, BH), 256, 0, stream>>>(kvqb, lr_sc, WKng, WVTb, AcThi, AcTlo, Bcb, Atil);
  seq_kernel<<<BH, 256, 0, stream>>>(AcThi, AcTlo, Bcb, Mpref, Mout);
  outphase_kernel<<<dim3(NCH, BH), 256, 0, stream>>>(kvqb, Mpref, WKng, WVTb, Atil, lr_sc, attn);

  // G2 = x @ Wg^T (fp32), then fused out = (attn @ Wo^T) * sigmoid(G2 + bg)
  gemm_kernel<2><<<dim3(64,6,1), 256, 0, stream>>>(xb, 768, 768, nullptr, 0, 0, 0,
                                                   Wgb, 768, 768, nullptr, nullptr, G2, 768);
  gemm_kernel<3><<<dim3(64,6,1), 256, 0, stream>>>(attn, 768, 768, nullptr, 0, 0, 0,
                                                   Wob, 768, 768, bg, G2, outF, 768);
}

// Round 4
// 309.179 us; speedup vs baseline: 6.9136x; 1.3007x over previous
//
#include <hip/hip_runtime.h>
#include <hip/hip_bf16.h>
#include <math.h>

#define B_ 4
#define S_ 2048
#define D_ 768
#define H_ 12
#define HD_ 64
#define P_ 768
#define M_ (B_*S_)   // 8192
#define NCH 32       // chunks per sequence
#define CH 64        // chunk length
#define BH (B_*H_)   // 48

typedef __hip_bfloat16 bf16;
typedef __attribute__((ext_vector_type(8))) short short8;
typedef __attribute__((ext_vector_type(4))) short s16x4;
typedef __attribute__((ext_vector_type(4))) float f32x4;

__device__ __forceinline__ float wave_reduce_sum(float v){
  #pragma unroll
  for (int off=32; off>0; off>>=1) v += __shfl_xor(v, off, 64);
  return v;
}
__device__ __forceinline__ float bf2f(bf16 h){ return __bfloat162float(h); }
__device__ __forceinline__ float us2f(unsigned short u){
  union{unsigned int i; float f;} z; z.i = ((unsigned int)u)<<16; return z.f;
}
// swizzled LDS [64][64] bf16 tiles (128B rows): byte ^= (row&7)<<4
__device__ __forceinline__ int adr(int row, int col){ return (row*128 + col*2) ^ ((row&7)<<4); }
__device__ __forceinline__ short8 lfrag(const char* base, int row, int col){
  return *(const short8*)(base + adr(row,col));
}
__device__ __forceinline__ short8 gfrag(const bf16* g, int row, int col){
  return *(const short8*)(g + row*64 + col);
}
__device__ __forceinline__ f32x4 MM(short8 a, short8 b, f32x4 c){
  return __builtin_amdgcn_mfma_f32_16x16x32_bf16(a, b, c, 0,0,0);
}
__device__ __forceinline__ short f2s(float v){ bf16 h = __float2bfloat16(v); return *(short*)&h; }
// packed C^T store: lane's 4 values C[m0..m0+3][n] -> tile[n][m0..m0+3]
__device__ __forceinline__ void stpk(char* b, int n, int m0, float v0,float v1,float v2,float v3){
  s16x4 p = { f2s(v0), f2s(v1), f2s(v2), f2s(v3) };
  *(s16x4*)(b + adr(n, m0)) = p;
}
__device__ __forceinline__ void stpk_hl(char* bh, char* bl, int n, int m0,
                                        float v0,float v1,float v2,float v3){
  float h0=bf2f(__float2bfloat16(v0)), h1=bf2f(__float2bfloat16(v1));
  float h2=bf2f(__float2bfloat16(v2)), h3=bf2f(__float2bfloat16(v3));
  stpk(bh, n, m0, h0,h1,h2,h3);
  stpk(bl, n, m0, v0-h0, v1-h1, v2-h2, v3-h3);
}
__device__ __forceinline__ float4 ldpk2(const char* bh, const char* bl, int n, int m0){
  s16x4 a = *(const s16x4*)(bh + adr(n,m0));
  s16x4 b = *(const s16x4*)(bl + adr(n,m0));
  return make_float4(us2f((unsigned short)a[0])+us2f((unsigned short)b[0]),
                     us2f((unsigned short)a[1])+us2f((unsigned short)b[1]),
                     us2f((unsigned short)a[2])+us2f((unsigned short)b[2]),
                     us2f((unsigned short)a[3])+us2f((unsigned short)b[3]));
}

// ---------------- merged weight/bias packing ----------------
__global__ __launch_bounds__(256) void pack_all_kernel(
    const float* __restrict__ km1,const float* __restrict__ vm1,const float* __restrict__ qm1,
    const float* __restrict__ Wk,const float* __restrict__ Wv,const float* __restrict__ Wq,
    const float* __restrict__ k2,const float* __restrict__ v2,const float* __restrict__ q2,
    const float* __restrict__ Wo,const float* __restrict__ Wg,
    const float* __restrict__ kb1,const float* __restrict__ vb1,const float* __restrict__ qb1,
    const float* __restrict__ kb2,const float* __restrict__ vb2,const float* __restrict__ qb2,
    const float* __restrict__ lnkg,const float* __restrict__ lnvg,const float* __restrict__ lnqg,
    const float* __restrict__ lnkb,const float* __restrict__ lnvb,const float* __restrict__ lnqb,
    bf16* __restrict__ Whb, bf16* __restrict__ Wkvqb, bf16* __restrict__ Wob,
    bf16* __restrict__ Wgb, float* __restrict__ biasb)
{
  int i = blockIdx.x*256 + threadIdx.x;
  if (i < 491520){                       // Wh pad 640x768
    int r = i/768, c = i%768;
    float v = 0.f;
    if (r < 192) v = km1[r*768+c];
    else if (r < 384) v = vm1[(r-192)*768+c];
    else if (r < 576) v = qm1[(r-384)*768+c];
    Whb[i] = __float2bfloat16(v);
  } else if (i < 2703360){               // Wkvq 2304x960
    int i2 = i - 491520;
    int r = i2/960, c = i2%960;
    int p = r/768, rr = r%768;
    const float* W  = (p==0)?Wk:(p==1)?Wv:Wq;
    const float* w2 = (p==0)?k2:(p==1)?v2:q2;
    float v = (c < 768) ? W[(size_t)rr*768+c] : 0.1f*w2[(size_t)rr*192 + (c-768)];
    Wkvqb[i2] = __float2bfloat16(v);
  } else if (i < 3293184){
    int i2 = i - 2703360;
    Wob[i2] = __float2bfloat16(Wo[i2]);
  } else if (i < 3883008){
    int i2 = i - 3293184;
    Wgb[i2] = __float2bfloat16(Wg[i2]);
  } else if (i < 3886272){
    int i2 = i - 3883008;                // 3264 floats
    if (i2 < 576){
      biasb[i2] = (i2<192)? kb1[i2] : (i2<384)? vb1[i2-192] : qb1[i2-384];
    } else if (i2 < 2880){
      int r = i2-576; int p = r/768, rr = r%768;
      const float* b2 = (p==0)?kb2:(p==1)?vb2:qb2;
      biasb[i2] = 0.1f*b2[rr];
    } else if (i2 < 3072){
      int k3 = i2-2880; int gg=k3/64, cc=k3%64;
      biasb[i2] = (gg==0?lnkg:gg==1?lnvg:lnqg)[cc];
    } else {
      int k3 = i2-3072; int gg=k3/64, cc=k3%64;
      biasb[i2] = (gg==0?lnkb:gg==1?lnvb:lnqb)[cc];
    }
  }
}

// ---------------- input layernorm ----------------
__global__ __launch_bounds__(256) void ln_in_kernel(const float* __restrict__ x, const float* __restrict__ g,
                                                    const float* __restrict__ bta,
                                                    bf16* __restrict__ xn, bf16* __restrict__ xb){
  int row = blockIdx.x;
  const float* xr = x + (size_t)row*D_;
  int t = threadIdx.x;
  float v0 = xr[t], v1 = xr[t+256], v2 = xr[t+512];
  float s  = v0+v1+v2;
  float sq = v0*v0+v1*v1+v2*v2;
  s = wave_reduce_sum(s); sq = wave_reduce_sum(sq);
  __shared__ float red[8];
  int w = t>>6;
  if ((t&63)==0){ red[w]=s; red[4+w]=sq; }
  __syncthreads();
  s  = red[0]+red[1]+red[2]+red[3];
  sq = red[4]+red[5]+red[6]+red[7];
  float mean = s*(1.f/D_);
  float var  = sq*(1.f/D_) - mean*mean;
  float inv  = rsqrtf(var + 1e-5f);
  bf16* xnr = xn + (size_t)row*D_;
  bf16* xbr = xb + (size_t)row*D_;
  xnr[t]     = __float2bfloat16((v0-mean)*inv*g[t]     + bta[t]);
  xnr[t+256] = __float2bfloat16((v1-mean)*inv*g[t+256] + bta[t+256]);
  xnr[t+512] = __float2bfloat16((v2-mean)*inv*g[t+512] + bta[t+512]);
  xbr[t] = __float2bfloat16(v0); xbr[t+256] = __float2bfloat16(v1); xbr[t+512] = __float2bfloat16(v2);
}

// ---------------- GEMM (bf16 MFMA, 128x128 tile, BK=32, 4 waves 2x2) ----------------
// MODE 0: gelu(val+bias[n]) -> bf16 [M][Nout]
// MODE 1: headLN(val+bias[g*768+n]) (+k-norm for g==0) -> bf16 scatter [g][b][h][s][hd]
// MODE 2: val -> fp32 [M][Nout]
// MODE 3: val * sigmoid(extra[m*768+n]+bias[n]) -> fp32 [M][Nout]
template<int MODE>
__global__ __launch_bounds__(256) void gemm_kernel(
    const bf16* __restrict__ A1, int lda1, int K1,
    const bf16* __restrict__ A2, int lda2, int K2, int a2_gstride,
    const bf16* __restrict__ Bw, int ldb, int ngroup,
    const float* __restrict__ bias, const float* __restrict__ extra,
    const float* __restrict__ lng, const float* __restrict__ lnb,
    void* __restrict__ outp, int Nout)
{
  __shared__ bf16 Asm[128*32];
  __shared__ bf16 Bsm[128*32];
  const int t = threadIdx.x;
  const int w = t>>6, L = t&63;
  const int m0 = blockIdx.x*128, n0 = blockIdx.y*128;
  const int g = blockIdx.z;
  const int wm = w>>1, wn = w&1;
  const int srow = t>>1;
  const int scol = (t&1)*16;
  const int Ktot = K1 + K2;

  f32x4 acc[4][4];
  #pragma unroll
  for (int i=0;i<4;i++)
    #pragma unroll
    for (int j=0;j<4;j++) acc[i][j] = (f32x4){0.f,0.f,0.f,0.f};

  const bf16* Brow = Bw + ((size_t)(g*ngroup + n0 + srow))*ldb;

  for (int k0=0; k0<Ktot; k0+=32){
    short8 a0,a1,b0,b1;
    if (k0 < K1){
      const bf16* ap = A1 + (size_t)(m0+srow)*lda1 + k0 + scol;
      a0 = *(const short8*)ap; a1 = *(const short8*)(ap+8);
    } else {
      const bf16* ap = A2 + (size_t)(m0+srow)*lda2 + (k0-K1) + g*a2_gstride + scol;
      a0 = *(const short8*)ap; a1 = *(const short8*)(ap+8);
    }
    {
      const bf16* bp = Brow + k0 + scol;
      b0 = *(const short8*)bp; b1 = *(const short8*)(bp+8);
    }
    __syncthreads();
    *(short8*)&Asm[srow*32+scol]   = a0; *(short8*)&Asm[srow*32+scol+8] = a1;
    *(short8*)&Bsm[srow*32+scol]   = b0; *(short8*)&Bsm[srow*32+scol+8] = b1;
    __syncthreads();
    short8 af[4], bfr[4];
    #pragma unroll
    for (int f=0;f<4;f++){
      af[f]  = *(const short8*)&Asm[(wm*64 + f*16 + (L&15))*32 + (L>>4)*8];
      bfr[f] = *(const short8*)&Bsm[(wn*64 + f*16 + (L&15))*32 + (L>>4)*8];
    }
    #pragma unroll
    for (int i=0;i<4;i++)
      #pragma unroll
      for (int j=0;j<4;j++)
        acc[i][j] = MM(af[i], bfr[j], acc[i][j]);
  }

  if (MODE==1){
    // fused per-head LN: each wave owns a full 64-wide head per row
    float gco[4], bco[4];
    #pragma unroll
    for (int j=0;j<4;j++){ int cc = j*16 + (L&15); gco[j] = lng[g*64+cc]; bco[j] = lnb[g*64+cc]; }
    #pragma unroll
    for (int i=0;i<4;i++){
      #pragma unroll
      for (int r=0;r<4;r++){
        float v[4];
        #pragma unroll
        for (int j=0;j<4;j++){
          int n = n0 + wn*64 + j*16 + (L&15);
          v[j] = acc[i][j][r] + bias[g*768 + n];
        }
        float s1 = v[0]+v[1]+v[2]+v[3];
        float s2 = v[0]*v[0]+v[1]*v[1]+v[2]*v[2]+v[3]*v[3];
        #pragma unroll
        for (int mk=1; mk<16; mk<<=1){ s1 += __shfl_xor(s1, mk, 64); s2 += __shfl_xor(s2, mk, 64); }
        float mean = s1*(1.f/64.f);
        float var  = s2*(1.f/64.f) - mean*mean;
        float inv  = rsqrtf(var + 1e-5f);
        float y[4];
        #pragma unroll
        for (int j=0;j<4;j++) y[j] = (v[j]-mean)*inv*gco[j] + bco[j];
        if (g==0){
          float n2 = y[0]*y[0]+y[1]*y[1]+y[2]*y[2]+y[3]*y[3];
          #pragma unroll
          for (int mk=1; mk<16; mk<<=1) n2 += __shfl_xor(n2, mk, 64);
          float sc = 1.f/(sqrtf(n2)+1e-6f);
          #pragma unroll
          for (int j=0;j<4;j++) y[j] *= sc;
        }
        int m = m0 + wm*64 + i*16 + (L>>4)*4 + r;
        int b_ = m>>11, s_ = m&2047;
        #pragma unroll
        for (int j=0;j<4;j++){
          int n = n0 + wn*64 + j*16 + (L&15);
          int h_ = n>>6, hd = n&63;
          ((bf16*)outp)[((((size_t)g*B_ + b_)*H_ + h_)*S_ + s_)*HD_ + hd] = __float2bfloat16(y[j]);
        }
      }
    }
  } else {
    #pragma unroll
    for (int i=0;i<4;i++){
      #pragma unroll
      for (int j=0;j<4;j++){
        #pragma unroll
        for (int r=0;r<4;r++){
          int m = m0 + wm*64 + i*16 + (L>>4)*4 + r;
          int n = n0 + wn*64 + j*16 + (L&15);
          float val = acc[i][j][r];
          if (MODE==0){
            if (n < Nout){
              val += bias[n];
              float ge = 0.5f*val*(1.f + erff(val*0.70710678f));
              ((bf16*)outp)[(size_t)m*Nout + n] = __float2bfloat16(ge);
            }
          } else if (MODE==2){
            ((float*)outp)[(size_t)m*Nout + n] = val;
          } else {
            float g2 = extra[(size_t)m*768 + n] + bias[n];
            float gate = 1.f/(1.f + __expf(-g2));
            ((float*)outp)[(size_t)m*Nout + n] = val * gate;
          }
        }
      }
    }
  }
}

// ---------------- chunk prep v2: all-MFMA, packed C^T stores ----------------
// T = (I+N)^-1 via 6-stage doubling; outputs (ABI as R3): WKng [t][j], WVTg [d][t],
// AcThi/lo [j][k], Bcb [d][j]  (Atil moved to outphase)
__global__ __launch_bounds__(256) void prep_kernel(
    const bf16* __restrict__ kvqb, const float* __restrict__ lr_scale,
    bf16* __restrict__ WKng, bf16* __restrict__ WVTg,
    bf16* __restrict__ AcThi, bf16* __restrict__ AcTlo, bf16* __restrict__ Bcb)
{
  __shared__ __align__(16) char T1[8192]; // Thi -> AcThi
  __shared__ __align__(16) char T2[8192]; // Tlo -> AcTlo
  __shared__ __align__(16) char T3[8192]; // P -> KnT -> WKn
  __shared__ __align__(16) char T4[8192]; // PT -> VT -> WKnT
  __shared__ __align__(16) char T5[8192]; // WVT -> Bc

  const int c = blockIdx.x, bh = blockIdx.y;
  const int h = bh % H_;
  const int t = threadIdx.x, w = t>>6, L = t&63;
  const size_t PS = (size_t)B_*H_*S_*HD_;
  const size_t base_k = (size_t)bh*S_*HD_ + (size_t)c*CH*HD_;
  const float lr = 0.2f/(1.f + __expf(-lr_scale[h]));
  const float beta = 1.f + lr;
  const size_t cb = ((size_t)bh*NCH + c)*4096;
  const bf16* Kg = kvqb + base_k;
  const bf16* Vg = kvqb + PS + base_k;

  const int fr = L&15, fc = (L>>4)*8;
  const int m0 = 16*w + (L>>4)*4;
  const int nb = L&15;   // n = 16*nt + nb

  // ---- phase 0: G = Kn Kn^T; init P=N, PT=N^T, T=I-N (hi/lo)
  {
    short8 aK[2];
    #pragma unroll
    for (int kk=0;kk<2;kk++) aK[kk] = gfrag(Kg, 16*w+fr, kk*32+fc);
    #pragma unroll
    for (int nt=0;nt<4;nt++){
      f32x4 g = (f32x4){0.f,0.f,0.f,0.f};
      #pragma unroll
      for (int kk=0;kk<2;kk++) g = MM(aK[kk], gfrag(Kg, 16*nt+fr, kk*32+fc), g);
      int n = 16*nt + nb;
      float pv[4], ptv[4], tv[4];
      #pragma unroll
      for (int r=0;r<4;r++){
        int m = m0 + r;
        float val = beta*g[r];
        pv[r]  = (n>m)? val : 0.f;
        ptv[r] = (m>n)? val : 0.f;
        tv[r]  = ((n==m)?1.f:0.f) - pv[r];
      }
      stpk(T3, n, m0, pv[0],pv[1],pv[2],pv[3]);
      stpk(T4, n, m0, ptv[0],ptv[1],ptv[2],ptv[3]);
      stpk_hl(T1, T2, n, m0, tv[0],tv[1],tv[2],tv[3]);
    }
  }
  __syncthreads();

  // ---- doubling: s>=1: T += T*N^(2^s); s<=4: square N
  #pragma unroll
  for (int s=0; s<6; ++s){
    const bool do_upd = (s>=1), do_sq = (s<=4);
    f32x4 upd[4], c1[4], c2[4];
    float4 tr[4];
    short8 aPT[2];
    #pragma unroll
    for (int kk=0;kk<2;kk++) aPT[kk] = lfrag(T4, 16*w+fr, kk*32+fc);
    if (do_upd){
      short8 b1[4][2], b2[4][2];
      #pragma unroll
      for (int nt=0;nt<4;nt++){
        #pragma unroll
        for (int kk=0;kk<2;kk++){
          b1[nt][kk] = lfrag(T1, 16*nt+fr, kk*32+fc);
          b2[nt][kk] = lfrag(T2, 16*nt+fr, kk*32+fc);
        }
        upd[nt] = (f32x4){0.f,0.f,0.f,0.f};
      }
      #pragma unroll
      for (int nt=0;nt<4;nt++)
        #pragma unroll
        for (int kk=0;kk<2;kk++){
          upd[nt] = MM(aPT[kk], b1[nt][kk], upd[nt]);
          upd[nt] = MM(aPT[kk], b2[nt][kk], upd[nt]);
        }
      #pragma unroll
      for (int nt=0;nt<4;nt++) tr[nt] = ldpk2(T1, T2, 16*nt+nb, m0);
    }
    if (do_sq){
      short8 aP[2], bPT[4][2], bP[4][2];
      #pragma unroll
      for (int kk=0;kk<2;kk++) aP[kk] = lfrag(T3, 16*w+fr, kk*32+fc);
      #pragma unroll
      for (int nt=0;nt<4;nt++){
        #pragma unroll
        for (int kk=0;kk<2;kk++){
          bPT[nt][kk] = lfrag(T4, 16*nt+fr, kk*32+fc);
          bP[nt][kk]  = lfrag(T3, 16*nt+fr, kk*32+fc);
        }
        c1[nt] = (f32x4){0.f,0.f,0.f,0.f};
        c2[nt] = (f32x4){0.f,0.f,0.f,0.f};
      }
      #pragma unroll
      for (int nt=0;nt<4;nt++)
        #pragma unroll
        for (int kk=0;kk<2;kk++){
          c1[nt] = MM(aP[kk],  bPT[nt][kk], c1[nt]);   // N^2p
          c2[nt] = MM(aPT[kk], bP[nt][kk],  c2[nt]);   // (N^2p)^T
        }
    }
    __syncthreads();
    if (do_upd){
      #pragma unroll
      for (int nt=0;nt<4;nt++){
        int n = 16*nt + nb;
        stpk_hl(T1, T2, n, m0, tr[nt].x+upd[nt][0], tr[nt].y+upd[nt][1],
                               tr[nt].z+upd[nt][2], tr[nt].w+upd[nt][3]);
      }
    }
    if (do_sq){
      #pragma unroll
      for (int nt=0;nt<4;nt++){
        int n = 16*nt + nb;
        stpk(T4, n, m0, c1[nt][0],c1[nt][1],c1[nt][2],c1[nt][3]);  // PT_new
        stpk(T3, n, m0, c2[nt][0],c2[nt][1],c2[nt][2],c2[nt][3]);  // P_new
      }
    }
    __syncthreads();
  }

  // ---- C1: MFMA transposes KnT->T3, VT->T4 (identity B-frags; no LDS reads)
  {
    short8 aKg[2], aVg[2];
    #pragma unroll
    for (int kk=0;kk<2;kk++){
      aKg[kk] = gfrag(Kg, 16*w+fr, kk*32+fc);
      aVg[kk] = gfrag(Vg, 16*w+fr, kk*32+fc);
    }
    #pragma unroll
    for (int nt=0;nt<4;nt++){
      f32x4 ck = (f32x4){0.f,0.f,0.f,0.f};
      f32x4 cv = (f32x4){0.f,0.f,0.f,0.f};
      int row = 16*nt + nb;
      #pragma unroll
      for (int kk=0;kk<2;kk++){
        short8 bi;
        int col0 = kk*32 + fc;
        #pragma unroll
        for (int e=0;e<8;e++) bi[e] = (col0+e == 16*nt+fr) ? (short)0x3F80 : (short)0;
        ck = MM(aKg[kk], bi, ck);
        cv = MM(aVg[kk], bi, cv);
      }
      stpk(T3, row, m0, ck[0],ck[1],ck[2],ck[3]);
      stpk(T4, row, m0, cv[0],cv[1],cv[2],cv[3]);
    }
  }
  __syncthreads();

  // ---- C2: WVT = (T*V)^T -> T5 ; WKnT = (T*Kn)^T -> T4
  {
    short8 a1[2], a2[2];
    #pragma unroll
    for (int kk=0;kk<2;kk++){
      a1[kk] = lfrag(T1, 16*w+fr, kk*32+fc);
      a2[kk] = lfrag(T2, 16*w+fr, kk*32+fc);
    }
    f32x4 cwv[4], cwk[4];
    #pragma unroll
    for (int nt=0;nt<4;nt++){ cwv[nt]=(f32x4){0.f,0.f,0.f,0.f}; cwk[nt]=(f32x4){0.f,0.f,0.f,0.f}; }
    #pragma unroll
    for (int nt=0;nt<4;nt++)
      #pragma unroll
      for (int kk=0;kk<2;kk++){
        short8 bV = lfrag(T4, 16*nt+fr, kk*32+fc);
        cwv[nt] = MM(a1[kk], bV, cwv[nt]);
        cwv[nt] = MM(a2[kk], bV, cwv[nt]);
      }
    #pragma unroll
    for (int nt=0;nt<4;nt++)
      #pragma unroll
      for (int kk=0;kk<2;kk++){
        short8 bK = lfrag(T3, 16*nt+fr, kk*32+fc);
        cwk[nt] = MM(a1[kk], bK, cwk[nt]);
        cwk[nt] = MM(a2[kk], bK, cwk[nt]);
      }
    __syncthreads();
    #pragma unroll
    for (int nt=0;nt<4;nt++){
      int n = 16*nt + nb;
      stpk(T5, n, m0, cwv[nt][0],cwv[nt][1],cwv[nt][2],cwv[nt][3]);
      stpk(T4, n, m0, cwk[nt][0],cwk[nt][1],cwk[nt][2],cwk[nt][3]);
    }
  }
  __syncthreads();

  // ---- C3: Bc -> T5, WKn -> T3, AcT(hi/lo) -> T1/T2 ; bounce WVT(T5) to global
  {
    int row = t>>2, seg = (t&3)*16;
    size_t go = cb + (size_t)row*64 + seg;
    *(short8*)(WVTg+go)   = *(const short8*)(T5 + adr(row,seg));
    *(short8*)(WVTg+go+8) = *(const short8*)(T5 + adr(row,seg+8));

    short8 aK2[2], aWKT[2];
    #pragma unroll
    for (int kk=0;kk<2;kk++){
      aK2[kk]  = lfrag(T3, 16*w+fr, kk*32+fc);
      aWKT[kk] = lfrag(T4, 16*w+fr, kk*32+fc);
    }
    f32x4 cBc[4], cWK[4], cAc[4];
    #pragma unroll
    for (int nt=0;nt<4;nt++){ cBc[nt]=(f32x4){0.f,0.f,0.f,0.f}; cWK[nt]=(f32x4){0.f,0.f,0.f,0.f}; cAc[nt]=(f32x4){0.f,0.f,0.f,0.f}; }
    #pragma unroll
    for (int nt=0;nt<4;nt++)
      #pragma unroll
      for (int kk=0;kk<2;kk++){
        short8 bWVT = lfrag(T5, 16*nt+fr, kk*32+fc);
        cBc[nt] = MM(aK2[kk], bWVT, cBc[nt]);
      }
    #pragma unroll
    for (int nt=0;nt<4;nt++)
      #pragma unroll
      for (int kk=0;kk<2;kk++){
        short8 b1 = lfrag(T1, 16*nt+fr, kk*32+fc);
        short8 b2 = lfrag(T2, 16*nt+fr, kk*32+fc);
        cWK[nt] = MM(aK2[kk], b1, cWK[nt]);
        cWK[nt] = MM(aK2[kk], b2, cWK[nt]);
      }
    #pragma unroll
    for (int nt=0;nt<4;nt++)
      #pragma unroll
      for (int kk=0;kk<2;kk++){
        short8 bK3 = lfrag(T3, 16*nt+fr, kk*32+fc);
        cAc[nt] = MM(aWKT[kk], bK3, cAc[nt]);
      }
    __syncthreads();
    #pragma unroll
    for (int nt=0;nt<4;nt++){
      int n = 16*nt + nb;
      stpk(T5, n, m0, lr*cBc[nt][0], lr*cBc[nt][1], lr*cBc[nt][2], lr*cBc[nt][3]);
      stpk(T3, n, m0, cWK[nt][0],cWK[nt][1],cWK[nt][2],cWK[nt][3]);
      float av[4];
      #pragma unroll
      for (int r=0;r<4;r++) av[r] = ((n==m0+r)?1.f:0.f) - beta*cAc[nt][r];
      stpk_hl(T1, T2, n, m0, av[0],av[1],av[2],av[3]);
    }
  }
  __syncthreads();

  // ---- C4: coalesced bounces to global
  {
    int row = t>>2, seg = (t&3)*16;
    size_t go = cb + (size_t)row*64 + seg;
    *(short8*)(AcThi+go)   = *(const short8*)(T1 + adr(row,seg));
    *(short8*)(AcThi+go+8) = *(const short8*)(T1 + adr(row,seg+8));
    *(short8*)(AcTlo+go)   = *(const short8*)(T2 + adr(row,seg));
    *(short8*)(AcTlo+go+8) = *(const short8*)(T2 + adr(row,seg+8));
    *(short8*)(Bcb+go)     = *(const short8*)(T5 + adr(row,seg));
    *(short8*)(Bcb+go+8)   = *(const short8*)(T5 + adr(row,seg+8));
    *(short8*)(WKng+go)    = *(const short8*)(T3 + adr(row,seg));
    *(short8*)(WKng+go+8)  = *(const short8*)(T3 + adr(row,seg+8));
  }
}

// ---------------- sequential chunk recurrence: M <- M*Ac + Bc (48 blocks) ----------------
__global__ __launch_bounds__(256) void seq_kernel(
    const bf16* __restrict__ AcThi, const bf16* __restrict__ AcTlo,
    const bf16* __restrict__ Bcb,
    bf16* __restrict__ Mpref, float* __restrict__ Mout)
{
  __shared__ __align__(16) char sM[4][2][2048];
  const int bh = blockIdx.x;
  const int t = threadIdx.x, w = t>>6, L = t&63;
  char* mhi = sM[w][0]; char* mlo = sM[w][1];
  const size_t cbase = (size_t)bh*NCH*4096;

  { float4 z = {0.f,0.f,0.f,0.f};
    #pragma unroll
    for (int i=0;i<2;i++){ ((float4*)mhi)[L + 64*i] = z; ((float4*)mlo)[L + 64*i] = z; } }
  { short8 z = {0,0,0,0,0,0,0,0};
    #pragma unroll
    for (int i=0;i<2;i++) ((short8*)(Mpref + cbase))[t + 256*i] = z; }

  short8 Xbh[4][2], Xbl[4][2]; float Xbc[4][4];
  short8 Ybh[4][2], Ybl[4][2]; float Ybc[4][4];

  auto loadf = [&](short8 (&fbh)[4][2], short8 (&fbl)[4][2], float (&fbc)[4][4], int c){
    size_t cb = cbase + (size_t)c*4096;
    #pragma unroll
    for (int nt=0;nt<4;nt++){
      #pragma unroll
      for (int kk=0;kk<2;kk++){
        size_t o = cb + (size_t)(16*nt + (L&15))*64 + kk*32 + (L>>4)*8;
        fbh[nt][kk] = *(const short8*)(AcThi + o);
        fbl[nt][kk] = *(const short8*)(AcTlo + o);
      }
      #pragma unroll
      for (int r=0;r<4;r++)
        fbc[nt][r] = us2f(*(const unsigned short*)(Bcb + cb + (size_t)(16*w + (L>>4)*4 + r)*64 + nt*16 + (L&15)));
    }
  };
  auto compute = [&](short8 (&fbh)[4][2], short8 (&fbl)[4][2], float (&fbc)[4][4], int c){
    short8 ah[2], al[2];
    #pragma unroll
    for (int kk=0;kk<2;kk++){
      ah[kk] = lfrag(mhi, L&15, kk*32 + (L>>4)*8);
      al[kk] = lfrag(mlo, L&15, kk*32 + (L>>4)*8);
    }
    #pragma unroll
    for (int nt=0;nt<4;nt++){
      f32x4 acc = { fbc[nt][0], fbc[nt][1], fbc[nt][2], fbc[nt][3] };
      acc = MM(ah[0], fbh[nt][0], acc);
      acc = MM(ah[1], fbh[nt][1], acc);
      acc = MM(ah[0], fbl[nt][0], acc);
      acc = MM(ah[1], fbl[nt][1], acc);
      acc = MM(al[0], fbh[nt][0], acc);
      acc = MM(al[1], fbh[nt][1], acc);
      #pragma unroll
      for (int r=0;r<4;r++){
        float f = acc[r];
        bf16 hi = __float2bfloat16(f);
        int lrow = (L>>4)*4 + r, col = nt*16 + (L&15);
        int off = ((lrow*128 + col*2) ^ ((lrow&7)<<4));
        *(bf16*)(mhi + off) = hi;
        *(bf16*)(mlo + off) = __float2bfloat16(f - bf2f(hi));
        if (c < NCH-1)
          Mpref[cbase + (size_t)(c+1)*4096 + (size_t)(16*w + lrow)*64 + col] = hi;
        else
          Mout[((size_t)bh*64 + 16*w + lrow)*64 + col] = f;
      }
    }
  };

  loadf(Xbh,Xbl,Xbc,0);
  for (int c=0;c<NCH;c+=2){
    loadf(Ybh,Ybl,Ybc,c+1);
    compute(Xbh,Xbl,Xbc,c);
    if (c+2 < NCH) loadf(Xbh,Xbl,Xbc,c+2);
    compute(Ybh,Ybl,Ybc,c+1);
  }
}

// ---------------- parallel output phase ----------------
// out = Q M0^T + Atil * U,  U = lr*WV - beta*(WKn M0^T);  Atil computed in-kernel
__global__ __launch_bounds__(256) void outphase_kernel(
    const bf16* __restrict__ kvqb, const bf16* __restrict__ Mpref,
    const bf16* __restrict__ WKng, const bf16* __restrict__ WVTb,
    const float* __restrict__ lr_scale, bf16* __restrict__ attn)
{
  __shared__ __align__(16) char sUT[8192];
  __shared__ __align__(16) char sAT[8192];
  const int c = blockIdx.x, bh = blockIdx.y;
  const int b = bh / H_, h = bh % H_;
  const int t = threadIdx.x, w = t>>6, L = t&63;
  const size_t PS = (size_t)B_*H_*S_*HD_;
  const size_t cb = ((size_t)bh*NCH + c)*4096;
  const size_t base_k = (size_t)bh*S_*HD_ + (size_t)c*CH*HD_;
  const bf16* Kg = kvqb + base_k;
  const bf16* Qg = kvqb + 2*PS + base_k;
  const float lr = 0.2f/(1.f + __expf(-lr_scale[h]));
  const float beta = 1.f + lr;
  const int fr = L&15, fc = (L>>4)*8;
  const int m0 = 16*w + (L>>4)*4;
  const int nb = L&15;

  // Atil tile: Z[t][i] = (i<t)? (Q Kn^T)[t][i] : 0   via TILE(Kn,Q) + packed C^T store
  {
    short8 aKn[2];
    #pragma unroll
    for (int kk=0;kk<2;kk++) aKn[kk] = gfrag(Kg, 16*w+fr, kk*32+fc);
    #pragma unroll
    for (int nt=0;nt<4;nt++){
      f32x4 cat = (f32x4){0.f,0.f,0.f,0.f};
      #pragma unroll
      for (int kk=0;kk<2;kk++) cat = MM(aKn[kk], gfrag(Qg, 16*nt+fr, kk*32+fc), cat);
      int n = 16*nt + nb;
      float v[4];
      #pragma unroll
      for (int r=0;r<4;r++) v[r] = (m0+r < n)? cat[r] : 0.f;
      stpk(sAT, n, m0, v[0],v[1],v[2],v[3]);
    }
  }

  short8 mb[4][2], qa[2], wa[2];
  #pragma unroll
  for (int kk=0;kk<2;kk++){
    qa[kk] = gfrag(Qg, 16*w+fr, kk*32+fc);
    wa[kk] = *(const short8*)(WKng + cb + (size_t)(16*w + fr)*64 + kk*32 + fc);
  }
  #pragma unroll
  for (int nt=0;nt<4;nt++)
    #pragma unroll
    for (int kk=0;kk<2;kk++)
      mb[nt][kk] = *(const short8*)(Mpref + cb + (size_t)(16*nt + fr)*64 + kk*32 + fc);
  f32x4 aout[4], ap[4];
  #pragma unroll
  for (int nt=0;nt<4;nt++){ aout[nt]=(f32x4){0.f,0.f,0.f,0.f}; ap[nt]=(f32x4){0.f,0.f,0.f,0.f}; }
  #pragma unroll
  for (int nt=0;nt<4;nt++)
    #pragma unroll
    for (int kk=0;kk<2;kk++){
      aout[nt] = MM(qa[kk], mb[nt][kk], aout[nt]);
      ap[nt]   = MM(wa[kk], mb[nt][kk], ap[nt]);
    }
  #pragma unroll
  for (int nt=0;nt<4;nt++){
    s16x4 wv4 = *(const s16x4*)(WVTb + cb + (size_t)(nt*16 + (L&15))*64 + 16*w + (L>>4)*4);
    short us[4];
    #pragma unroll
    for (int r=0;r<4;r++){
      float wv = us2f((unsigned short)wv4[r]);
      us[r] = f2s(lr*wv - beta*ap[nt][r]);
    }
    int d = nt*16 + (L&15);
    int i0 = 16*w + (L>>4)*4;
    s16x4 pk = { us[0], us[1], us[2], us[3] };
    *(s16x4*)(sUT + adr(d, i0)) = pk;
  }
  __syncthreads();
  short8 ta[2], ub[4][2];
  #pragma unroll
  for (int kk=0;kk<2;kk++)
    ta[kk] = lfrag(sAT, 16*w+fr, kk*32+fc);
  #pragma unroll
  for (int nt=0;nt<4;nt++)
    #pragma unroll
    for (int kk=0;kk<2;kk++)
      ub[nt][kk] = lfrag(sUT, 16*nt + fr, kk*32 + fc);
  #pragma unroll
  for (int nt=0;nt<4;nt++)
    #pragma unroll
    for (int kk=0;kk<2;kk++)
      aout[nt] = MM(ta[kk], ub[nt][kk], aout[nt]);
  #pragma unroll
  for (int nt=0;nt<4;nt++)
    #pragma unroll
    for (int r=0;r<4;r++)
      attn[((size_t)b*S_ + (size_t)c*CH + 16*w + (L>>4)*4 + r)*P_ + h*HD_ + nt*16 + (L&15)]
        = __float2bfloat16(aout[nt][r]);
}

extern "C" void kernel_launch(void* const* d_in, const int* in_sizes, int n_in,
                              void* d_out, int out_size, void* d_ws, size_t ws_size,
                              hipStream_t stream)
{
  const float* x     = (const float*)d_in[0];
  const float* ln_g  = (const float*)d_in[1];
  const float* ln_b  = (const float*)d_in[2];
  const float* Wk    = (const float*)d_in[3];
  const float* Wv    = (const float*)d_in[4];
  const float* Wq    = (const float*)d_in[5];
  const float* km_w1 = (const float*)d_in[6];  const float* km_b1 = (const float*)d_in[7];
  const float* km_w2 = (const float*)d_in[8];  const float* km_b2 = (const float*)d_in[9];
  const float* vm_w1 = (const float*)d_in[10]; const float* vm_b1 = (const float*)d_in[11];
  const float* vm_w2 = (const float*)d_in[12]; const float* vm_b2 = (const float*)d_in[13];
  const float* qm_w1 = (const float*)d_in[14]; const float* qm_b1 = (const float*)d_in[15];
  const float* qm_w2 = (const float*)d_in[16]; const float* qm_b2 = (const float*)d_in[17];
  const float* lnk_g = (const float*)d_in[18]; const float* lnk_b = (const float*)d_in[19];
  const float* lnv_g = (const float*)d_in[20]; const float* lnv_b = (const float*)d_in[21];
  const float* lnq_g = (const float*)d_in[22]; const float* lnq_b = (const float*)d_in[23];
  const float* Wo    = (const float*)d_in[24];
  const float* lr_sc = (const float*)d_in[25];
  const float* Wg    = (const float*)d_in[26];
  const float* bg    = (const float*)d_in[27];

  const size_t CHB = (size_t)BH*NCH*4096;

  char* ws = (char*)d_ws;
  size_t o = 0;
  bf16* xnb   = (bf16*)(ws + o); o += (size_t)M_*D_*2;
  bf16* xb    = (bf16*)(ws + o); o += (size_t)M_*D_*2;
  bf16* Hb    = (bf16*)(ws + o); o += (size_t)M_*576*2;
  bf16* kvqb  = (bf16*)(ws + o); o += (size_t)3*M_*P_*2;
  bf16* attn  = (bf16*)(ws + o); o += (size_t)M_*P_*2;
  size_t o_p = o;
  bf16* AcThi = (bf16*)(ws + o); o += CHB*2;
  bf16* AcTlo = (bf16*)(ws + o); o += CHB*2;
  bf16* Bcb   = (bf16*)(ws + o); o += CHB*2;
  bf16* WVTb  = (bf16*)(ws + o); o += CHB*2;
  bf16* WKng  = (bf16*)(ws + o); o += CHB*2;
  bf16* Mpref = (bf16*)(ws + o); o += CHB*2;
  bf16* Whb   = (bf16*)(ws + o); o += (size_t)640*768*2;
  bf16* Wkvqb = (bf16*)(ws + o); o += (size_t)2304*960*2;
  bf16* Wob   = (bf16*)(ws + o); o += (size_t)768*768*2;
  bf16* Wgb   = (bf16*)(ws + o); o += (size_t)768*768*2;
  float* biasb= (float*)(ws + o); o += 3264*4;
  // G2 overlays AcThi+AcTlo (dead after seq; outphase doesn't touch them)
  float* G2   = (float*)(ws + o_p);

  float* outF = (float*)d_out;
  float* Mout = outF + (size_t)M_*D_;

  pack_all_kernel<<<15181, 256, 0, stream>>>(
      km_w1, vm_w1, qm_w1, Wk, Wv, Wq, km_w2, vm_w2, qm_w2, Wo, Wg,
      km_b1, vm_b1, qm_b1, km_b2, vm_b2, qm_b2,
      lnk_g, lnv_g, lnq_g, lnk_b, lnv_b, lnq_b,
      Whb, Wkvqb, Wob, Wgb, biasb);

  ln_in_kernel<<<M_, 256, 0, stream>>>(x, ln_g, ln_b, xnb, xb);

  gemm_kernel<0><<<dim3(64,5,1), 256, 0, stream>>>(xnb, 768, 768, nullptr, 0, 0, 0,
                                                   Whb, 768, 640, biasb, nullptr, nullptr, nullptr, Hb, 576);
  gemm_kernel<1><<<dim3(64,6,3), 256, 0, stream>>>(xnb, 768, 768, Hb, 576, 192, 192,
                                                   Wkvqb, 960, 768, biasb + 576, nullptr,
                                                   biasb + 2880, biasb + 3072, kvqb, 768);

  prep_kernel<<<dim3(NCH, BH), 256, 0, stream>>>(kvqb, lr_sc, WKng, WVTb, AcThi, AcTlo, Bcb);
  seq_kernel<<<BH, 256, 0, stream>>>(AcThi, AcTlo, Bcb, Mpref, Mout);
  outphase_kernel<<<dim3(NCH, BH), 256, 0, stream>>>(kvqb, Mpref, WKng, WVTb, lr_sc, attn);

  // G2 = x @ Wg^T (fp32), then fused out = (attn @ Wo^T) * sigmoid(G2 + bg)
  gemm_kernel<2><<<dim3(64,6,1), 256, 0, stream>>>(xb, 768, 768, nullptr, 0, 0, 0,
                                                   Wgb, 768, 768, nullptr, nullptr, nullptr, nullptr, G2, 768);
  gemm_kernel<3><<<dim3(64,6,1), 256, 0, stream>>>(attn, 768, 768, nullptr, 0, 0, 0,
                                                   Wob, 768, 768, bg, G2, nullptr, nullptr, outF, 768);
}

// Round 6
// 286.544 us; speedup vs baseline: 7.4597x; 1.0790x over previous
//
#include <hip/hip_runtime.h>
#include <hip/hip_bf16.h>
#include <math.h>

#define B_ 4
#define S_ 2048
#define D_ 768
#define H_ 12
#define HD_ 64
#define P_ 768
#define M_ (B_*S_)   // 8192
#define NCH 32       // chunks per sequence
#define CH 64        // chunk length
#define BH (B_*H_)   // 48

typedef __hip_bfloat16 bf16;
typedef __attribute__((ext_vector_type(8))) short short8;
typedef __attribute__((ext_vector_type(4))) short s16x4;
typedef __attribute__((ext_vector_type(4))) float f32x4;

__device__ __forceinline__ float wave_reduce_sum(float v){
  #pragma unroll
  for (int off=32; off>0; off>>=1) v += __shfl_xor(v, off, 64);
  return v;
}
__device__ __forceinline__ float bf2f(bf16 h){ return __bfloat162float(h); }
__device__ __forceinline__ float us2f(unsigned short u){
  union{unsigned int i; float f;} z; z.i = ((unsigned int)u)<<16; return z.f;
}
// swizzled LDS [64][64] bf16 tiles (128B rows): byte ^= (row&7)<<4
__device__ __forceinline__ int adr(int row, int col){ return (row*128 + col*2) ^ ((row&7)<<4); }
__device__ __forceinline__ short8 lfrag(const char* base, int row, int col){
  return *(const short8*)(base + adr(row,col));
}
__device__ __forceinline__ short8 gfrag(const bf16* g, int row, int col){
  return *(const short8*)(g + row*64 + col);
}
__device__ __forceinline__ f32x4 MM(short8 a, short8 b, f32x4 c){
  return __builtin_amdgcn_mfma_f32_16x16x32_bf16(a, b, c, 0,0,0);
}
__device__ __forceinline__ short f2s(float v){ bf16 h = __float2bfloat16(v); return *(short*)&h; }
// packed C^T store: lane's 4 values C[m0..m0+3][n] -> tile[n][m0..m0+3]
__device__ __forceinline__ void stpk(char* b, int n, int m0, float v0,float v1,float v2,float v3){
  s16x4 p = { f2s(v0), f2s(v1), f2s(v2), f2s(v3) };
  *(s16x4*)(b + adr(n, m0)) = p;
}
__device__ __forceinline__ void stpk_hl(char* bh, char* bl, int n, int m0,
                                        float v0,float v1,float v2,float v3){
  float h0=bf2f(__float2bfloat16(v0)), h1=bf2f(__float2bfloat16(v1));
  float h2=bf2f(__float2bfloat16(v2)), h3=bf2f(__float2bfloat16(v3));
  stpk(bh, n, m0, h0,h1,h2,h3);
  stpk(bl, n, m0, v0-h0, v1-h1, v2-h2, v3-h3);
}
__device__ __forceinline__ float4 ldpk2(const char* bh, const char* bl, int n, int m0){
  s16x4 a = *(const s16x4*)(bh + adr(n,m0));
  s16x4 b = *(const s16x4*)(bl + adr(n,m0));
  return make_float4(us2f((unsigned short)a[0])+us2f((unsigned short)b[0]),
                     us2f((unsigned short)a[1])+us2f((unsigned short)b[1]),
                     us2f((unsigned short)a[2])+us2f((unsigned short)b[2]),
                     us2f((unsigned short)a[3])+us2f((unsigned short)b[3]));
}
// async global->LDS, 16B per lane, LDS dest = wave-uniform base + lane*16
__device__ __forceinline__ void gl_lds(const bf16* g, const bf16* l){
  __builtin_amdgcn_global_load_lds(
      (const __attribute__((address_space(1))) void*)g,
      (__attribute__((address_space(3))) void*)l, 16, 0, 0);
}

// ---------------- merged weight/bias packing ----------------
__global__ __launch_bounds__(256) void pack_all_kernel(
    const float* __restrict__ km1,const float* __restrict__ vm1,const float* __restrict__ qm1,
    const float* __restrict__ Wk,const float* __restrict__ Wv,const float* __restrict__ Wq,
    const float* __restrict__ k2,const float* __restrict__ v2,const float* __restrict__ q2,
    const float* __restrict__ Wo,const float* __restrict__ Wg,
    const float* __restrict__ kb1,const float* __restrict__ vb1,const float* __restrict__ qb1,
    const float* __restrict__ kb2,const float* __restrict__ vb2,const float* __restrict__ qb2,
    const float* __restrict__ lnkg,const float* __restrict__ lnvg,const float* __restrict__ lnqg,
    const float* __restrict__ lnkb,const float* __restrict__ lnvb,const float* __restrict__ lnqb,
    bf16* __restrict__ Whb, bf16* __restrict__ Wkvqb, bf16* __restrict__ Wob,
    bf16* __restrict__ Wgb, float* __restrict__ biasb)
{
  int i = blockIdx.x*256 + threadIdx.x;
  if (i < 491520){                       // Wh pad 640x768
    int r = i/768, c = i%768;
    float v = 0.f;
    if (r < 192) v = km1[r*768+c];
    else if (r < 384) v = vm1[(r-192)*768+c];
    else if (r < 576) v = qm1[(r-384)*768+c];
    Whb[i] = __float2bfloat16(v);
  } else if (i < 2703360){               // Wkvq 2304x960
    int i2 = i - 491520;
    int r = i2/960, c = i2%960;
    int p = r/768, rr = r%768;
    const float* W  = (p==0)?Wk:(p==1)?Wv:Wq;
    const float* w2 = (p==0)?k2:(p==1)?v2:q2;
    float v = (c < 768) ? W[(size_t)rr*768+c] : 0.1f*w2[(size_t)rr*192 + (c-768)];
    Wkvqb[i2] = __float2bfloat16(v);
  } else if (i < 3293184){
    int i2 = i - 2703360;
    Wob[i2] = __float2bfloat16(Wo[i2]);
  } else if (i < 3883008){
    int i2 = i - 3293184;
    Wgb[i2] = __float2bfloat16(Wg[i2]);
  } else if (i < 3886272){
    int i2 = i - 3883008;                // 3264 floats
    if (i2 < 576){
      biasb[i2] = (i2<192)? kb1[i2] : (i2<384)? vb1[i2-192] : qb1[i2-384];
    } else if (i2 < 2880){
      int r = i2-576; int p = r/768, rr = r%768;
      const float* b2 = (p==0)?kb2:(p==1)?vb2:qb2;
      biasb[i2] = 0.1f*b2[rr];
    } else if (i2 < 3072){
      int k3 = i2-2880; int gg=k3/64, cc=k3%64;
      biasb[i2] = (gg==0?lnkg:gg==1?lnvg:lnqg)[cc];
    } else {
      int k3 = i2-3072; int gg=k3/64, cc=k3%64;
      biasb[i2] = (gg==0?lnkb:gg==1?lnvb:lnqb)[cc];
    }
  }
}

// ---------------- input layernorm ----------------
__global__ __launch_bounds__(256) void ln_in_kernel(const float* __restrict__ x, const float* __restrict__ g,
                                                    const float* __restrict__ bta,
                                                    bf16* __restrict__ xn, bf16* __restrict__ xb){
  int row = blockIdx.x;
  const float* xr = x + (size_t)row*D_;
  int t = threadIdx.x;
  float v0 = xr[t], v1 = xr[t+256], v2 = xr[t+512];
  float s  = v0+v1+v2;
  float sq = v0*v0+v1*v1+v2*v2;
  s = wave_reduce_sum(s); sq = wave_reduce_sum(sq);
  __shared__ float red[8];
  int w = t>>6;
  if ((t&63)==0){ red[w]=s; red[4+w]=sq; }
  __syncthreads();
  s  = red[0]+red[1]+red[2]+red[3];
  sq = red[4]+red[5]+red[6]+red[7];
  float mean = s*(1.f/D_);
  float var  = sq*(1.f/D_) - mean*mean;
  float inv  = rsqrtf(var + 1e-5f);
  bf16* xnr = xn + (size_t)row*D_;
  bf16* xbr = xb + (size_t)row*D_;
  xnr[t]     = __float2bfloat16((v0-mean)*inv*g[t]     + bta[t]);
  xnr[t+256] = __float2bfloat16((v1-mean)*inv*g[t+256] + bta[t+256]);
  xnr[t+512] = __float2bfloat16((v2-mean)*inv*g[t+512] + bta[t+512]);
  xbr[t] = __float2bfloat16(v0); xbr[t+256] = __float2bfloat16(v1); xbr[t+512] = __float2bfloat16(v2);
}

// ---------------- GEMM v3: 128x128 tile, BK=64, DOUBLE-BUFFERED global_load_lds ----------------
// T3 "minimum 2-phase" recipe: prologue STAGE(buf0); per tile {vmcnt(0)+barrier ->
// STAGE(buf^1, next) -> MFMA(buf)}. Prefetch writes the buffer nobody reads -> race-free.
// LDS rows 128B; content slot c stored at slot c^(row&7); source col pre-swizzled (rule #21).
// MODE 0: gelu(val+bias[n]) -> bf16 [M][Nout]
// MODE 1: headLN(val+bias[g*768+n]) (+k-norm for g==0) -> bf16 scatter [g][b][h][s][hd]
// MODE 2: val -> fp32 [M][Nout]
// MODE 3: val * sigmoid(extra[m*768+n]+bias[n]) -> fp32 [M][Nout]
template<int MODE>
__global__ __launch_bounds__(256) void gemm_kernel(
    const bf16* __restrict__ A1, int lda1, int K1,
    const bf16* __restrict__ A2, int lda2, int K2, int a2_gstride,
    const bf16* __restrict__ Bw, int ldb, int ngroup,
    const float* __restrict__ bias, const float* __restrict__ extra,
    const float* __restrict__ lng, const float* __restrict__ lnb,
    void* __restrict__ outp, int Nout)
{
  __shared__ bf16 Asm[2][128*64];
  __shared__ bf16 Bsm[2][128*64];
  const int t = threadIdx.x;
  const int w = t>>6, L = t&63;
  const int m0 = blockIdx.x*128, n0 = blockIdx.y*128;
  const int g = blockIdx.z;
  const int wm = w>>1, wn = w&1;
  const int Ktot = K1 + K2;
  const int nk = Ktot >> 6;

  // staging: 4 issues/thread/tile; lane L covers row w*32+i*8+(L>>3), LDS slot L&7.
  // stored content slot = (L&7) ^ (row&7); row&7 == (L>>3)&7 (i*8 drops out).
  const int srow_base = w*32 + (L>>3);
  const int scol = ((L&7) ^ ((L>>3)&7))*8;   // pre-swizzled source column (elements)

  // frag read offsets (elements), constant across K-loop
  int aoff[4][2], boff[4][2];
  #pragma unroll
  for (int f=0;f<4;f++){
    int arow = wm*64 + f*16 + (L&15);
    int brow = wn*64 + f*16 + (L&15);
    #pragma unroll
    for (int q=0;q<2;q++){
      int slot = q*4 + (L>>4);
      aoff[f][q] = arow*64 + ((slot ^ (arow&7))*8);
      boff[f][q] = brow*64 + ((slot ^ (brow&7))*8);
    }
  }

  const bf16* BrowBase = Bw + (size_t)(g*ngroup + n0)*ldb;

  auto STAGE = [&](int buf, int k0){
    const bf16* Ab; int lda; int acol;
    if (k0 < K1){ Ab = A1; lda = lda1; acol = k0 + scol; }
    else        { Ab = A2; lda = lda2; acol = (k0-K1) + g*a2_gstride + scol; }
    #pragma unroll
    for (int i=0;i<4;i++){
      int row = srow_base + i*8;
      gl_lds(Ab + (size_t)(m0+row)*lda + acol,       &Asm[buf][w*2048 + i*512]);
      gl_lds(BrowBase + (size_t)row*ldb + k0 + scol, &Bsm[buf][w*2048 + i*512]);
    }
  };

  f32x4 acc[4][4];
  #pragma unroll
  for (int i=0;i<4;i++)
    #pragma unroll
    for (int j=0;j<4;j++) acc[i][j] = (f32x4){0.f,0.f,0.f,0.f};

  STAGE(0, 0);
  int cur = 0;
  for (int kt=0; kt<nk; ++kt){
    asm volatile("s_waitcnt vmcnt(0)" ::: "memory");  // DMA of tile kt landed
    __syncthreads();                                  // visible to all waves; prev reads done
    if (kt+1 < nk) STAGE(cur^1, (kt+1)<<6);           // prefetch into the other buffer
    const bf16* As = Asm[cur];
    const bf16* Bs = Bsm[cur];
    #pragma unroll
    for (int q=0;q<2;q++){
      short8 af[4], bfr[4];
      #pragma unroll
      for (int f=0;f<4;f++){
        af[f]  = *(const short8*)&As[aoff[f][q]];
        bfr[f] = *(const short8*)&Bs[boff[f][q]];
      }
      #pragma unroll
      for (int i=0;i<4;i++)
        #pragma unroll
        for (int j=0;j<4;j++)
          acc[i][j] = MM(af[i], bfr[j], acc[i][j]);
    }
    cur ^= 1;
  }

  if (MODE==1){
    // fused per-head LN: each wave owns a full 64-wide head per row
    float gco[4], bco[4];
    #pragma unroll
    for (int j=0;j<4;j++){ int cc = j*16 + (L&15); gco[j] = lng[g*64+cc]; bco[j] = lnb[g*64+cc]; }
    #pragma unroll
    for (int i=0;i<4;i++){
      #pragma unroll
      for (int r=0;r<4;r++){
        float v[4];
        #pragma unroll
        for (int j=0;j<4;j++){
          int n = n0 + wn*64 + j*16 + (L&15);
          v[j] = acc[i][j][r] + bias[g*768 + n];
        }
        float s1 = v[0]+v[1]+v[2]+v[3];
        float s2 = v[0]*v[0]+v[1]*v[1]+v[2]*v[2]+v[3]*v[3];
        #pragma unroll
        for (int mk=1; mk<16; mk<<=1){ s1 += __shfl_xor(s1, mk, 64); s2 += __shfl_xor(s2, mk, 64); }
        float mean = s1*(1.f/64.f);
        float var  = s2*(1.f/64.f) - mean*mean;
        float inv  = rsqrtf(var + 1e-5f);
        float y[4];
        #pragma unroll
        for (int j=0;j<4;j++) y[j] = (v[j]-mean)*inv*gco[j] + bco[j];
        if (g==0){
          float n2 = y[0]*y[0]+y[1]*y[1]+y[2]*y[2]+y[3]*y[3];
          #pragma unroll
          for (int mk=1; mk<16; mk<<=1) n2 += __shfl_xor(n2, mk, 64);
          float sc = 1.f/(sqrtf(n2)+1e-6f);
          #pragma unroll
          for (int j=0;j<4;j++) y[j] *= sc;
        }
        int m = m0 + wm*64 + i*16 + (L>>4)*4 + r;
        int b_ = m>>11, s_ = m&2047;
        #pragma unroll
        for (int j=0;j<4;j++){
          int n = n0 + wn*64 + j*16 + (L&15);
          int h_ = n>>6, hd = n&63;
          ((bf16*)outp)[((((size_t)g*B_ + b_)*H_ + h_)*S_ + s_)*HD_ + hd] = __float2bfloat16(y[j]);
        }
      }
    }
  } else {
    #pragma unroll
    for (int i=0;i<4;i++){
      #pragma unroll
      for (int j=0;j<4;j++){
        #pragma unroll
        for (int r=0;r<4;r++){
          int m = m0 + wm*64 + i*16 + (L>>4)*4 + r;
          int n = n0 + wn*64 + j*16 + (L&15);
          float val = acc[i][j][r];
          if (MODE==0){
            if (n < Nout){
              val += bias[n];
              float ge = 0.5f*val*(1.f + erff(val*0.70710678f));
              ((bf16*)outp)[(size_t)m*Nout + n] = __float2bfloat16(ge);
            }
          } else if (MODE==2){
            ((float*)outp)[(size_t)m*Nout + n] = val;
          } else {
            float g2 = extra[(size_t)m*768 + n] + bias[n];
            float gate = 1.f/(1.f + __expf(-g2));
            ((float*)outp)[(size_t)m*Nout + n] = val * gate;
          }
        }
      }
    }
  }
}

// ---------------- chunk prep v2: all-MFMA, packed C^T stores ----------------
__global__ __launch_bounds__(256) void prep_kernel(
    const bf16* __restrict__ kvqb, const float* __restrict__ lr_scale,
    bf16* __restrict__ WKng, bf16* __restrict__ WVTg,
    bf16* __restrict__ AcThi, bf16* __restrict__ AcTlo, bf16* __restrict__ Bcb)
{
  __shared__ __align__(16) char T1[8192]; // Thi -> AcThi
  __shared__ __align__(16) char T2[8192]; // Tlo -> AcTlo
  __shared__ __align__(16) char T3[8192]; // P -> KnT -> WKn
  __shared__ __align__(16) char T4[8192]; // PT -> VT -> WKnT
  __shared__ __align__(16) char T5[8192]; // WVT -> Bc

  const int c = blockIdx.x, bh = blockIdx.y;
  const int h = bh % H_;
  const int t = threadIdx.x, w = t>>6, L = t&63;
  const size_t PS = (size_t)B_*H_*S_*HD_;
  const size_t base_k = (size_t)bh*S_*HD_ + (size_t)c*CH*HD_;
  const float lr = 0.2f/(1.f + __expf(-lr_scale[h]));
  const float beta = 1.f + lr;
  const size_t cb = ((size_t)bh*NCH + c)*4096;
  const bf16* Kg = kvqb + base_k;
  const bf16* Vg = kvqb + PS + base_k;

  const int fr = L&15, fc = (L>>4)*8;
  const int m0 = 16*w + (L>>4)*4;
  const int nb = L&15;   // n = 16*nt + nb

  // ---- phase 0: G = Kn Kn^T; init P=N, PT=N^T, T=I-N (hi/lo)
  {
    short8 aK[2];
    #pragma unroll
    for (int kk=0;kk<2;kk++) aK[kk] = gfrag(Kg, 16*w+fr, kk*32+fc);
    #pragma unroll
    for (int nt=0;nt<4;nt++){
      f32x4 g = (f32x4){0.f,0.f,0.f,0.f};
      #pragma unroll
      for (int kk=0;kk<2;kk++) g = MM(aK[kk], gfrag(Kg, 16*nt+fr, kk*32+fc), g);
      int n = 16*nt + nb;
      float pv[4], ptv[4], tv[4];
      #pragma unroll
      for (int r=0;r<4;r++){
        int m = m0 + r;
        float val = beta*g[r];
        pv[r]  = (n>m)? val : 0.f;
        ptv[r] = (m>n)? val : 0.f;
        tv[r]  = ((n==m)?1.f:0.f) - pv[r];
      }
      stpk(T3, n, m0, pv[0],pv[1],pv[2],pv[3]);
      stpk(T4, n, m0, ptv[0],ptv[1],ptv[2],ptv[3]);
      stpk_hl(T1, T2, n, m0, tv[0],tv[1],tv[2],tv[3]);
    }
  }
  __syncthreads();

  // ---- doubling: s>=1: T += T*N^(2^s); s<=4: square N
  #pragma unroll
  for (int s=0; s<6; ++s){
    const bool do_upd = (s>=1), do_sq = (s<=4);
    f32x4 upd[4], c1[4], c2[4];
    float4 tr[4];
    short8 aPT[2];
    #pragma unroll
    for (int kk=0;kk<2;kk++) aPT[kk] = lfrag(T4, 16*w+fr, kk*32+fc);
    if (do_upd){
      short8 b1[4][2], b2[4][2];
      #pragma unroll
      for (int nt=0;nt<4;nt++){
        #pragma unroll
        for (int kk=0;kk<2;kk++){
          b1[nt][kk] = lfrag(T1, 16*nt+fr, kk*32+fc);
          b2[nt][kk] = lfrag(T2, 16*nt+fr, kk*32+fc);
        }
        upd[nt] = (f32x4){0.f,0.f,0.f,0.f};
      }
      #pragma unroll
      for (int nt=0;nt<4;nt++)
        #pragma unroll
        for (int kk=0;kk<2;kk++){
          upd[nt] = MM(aPT[kk], b1[nt][kk], upd[nt]);
          upd[nt] = MM(aPT[kk], b2[nt][kk], upd[nt]);
        }
      #pragma unroll
      for (int nt=0;nt<4;nt++) tr[nt] = ldpk2(T1, T2, 16*nt+nb, m0);
    }
    if (do_sq){
      short8 aP[2], bPT[4][2], bP[4][2];
      #pragma unroll
      for (int kk=0;kk<2;kk++) aP[kk] = lfrag(T3, 16*w+fr, kk*32+fc);
      #pragma unroll
      for (int nt=0;nt<4;nt++){
        #pragma unroll
        for (int kk=0;kk<2;kk++){
          bPT[nt][kk] = lfrag(T4, 16*nt+fr, kk*32+fc);
          bP[nt][kk]  = lfrag(T3, 16*nt+fr, kk*32+fc);
        }
        c1[nt] = (f32x4){0.f,0.f,0.f,0.f};
        c2[nt] = (f32x4){0.f,0.f,0.f,0.f};
      }
      #pragma unroll
      for (int nt=0;nt<4;nt++)
        #pragma unroll
        for (int kk=0;kk<2;kk++){
          c1[nt] = MM(aP[kk],  bPT[nt][kk], c1[nt]);   // N^2p
          c2[nt] = MM(aPT[kk], bP[nt][kk],  c2[nt]);   // (N^2p)^T
        }
    }
    __syncthreads();
    if (do_upd){
      #pragma unroll
      for (int nt=0;nt<4;nt++){
        int n = 16*nt + nb;
        stpk_hl(T1, T2, n, m0, tr[nt].x+upd[nt][0], tr[nt].y+upd[nt][1],
                               tr[nt].z+upd[nt][2], tr[nt].w+upd[nt][3]);
      }
    }
    if (do_sq){
      #pragma unroll
      for (int nt=0;nt<4;nt++){
        int n = 16*nt + nb;
        stpk(T4, n, m0, c1[nt][0],c1[nt][1],c1[nt][2],c1[nt][3]);  // PT_new
        stpk(T3, n, m0, c2[nt][0],c2[nt][1],c2[nt][2],c2[nt][3]);  // P_new
      }
    }
    __syncthreads();
  }

  // ---- C1: MFMA transposes KnT->T3, VT->T4 (identity B-frags; no LDS reads)
  {
    short8 aKg[2], aVg[2];
    #pragma unroll
    for (int kk=0;kk<2;kk++){
      aKg[kk] = gfrag(Kg, 16*w+fr, kk*32+fc);
      aVg[kk] = gfrag(Vg, 16*w+fr, kk*32+fc);
    }
    #pragma unroll
    for (int nt=0;nt<4;nt++){
      f32x4 ck = (f32x4){0.f,0.f,0.f,0.f};
      f32x4 cv = (f32x4){0.f,0.f,0.f,0.f};
      int row = 16*nt + nb;
      #pragma unroll
      for (int kk=0;kk<2;kk++){
        short8 bi;
        int col0 = kk*32 + fc;
        #pragma unroll
        for (int e=0;e<8;e++) bi[e] = (col0+e == 16*nt+fr) ? (short)0x3F80 : (short)0;
        ck = MM(aKg[kk], bi, ck);
        cv = MM(aVg[kk], bi, cv);
      }
      stpk(T3, row, m0, ck[0],ck[1],ck[2],ck[3]);
      stpk(T4, row, m0, cv[0],cv[1],cv[2],cv[3]);
    }
  }
  __syncthreads();

  // ---- C2: WVT = (T*V)^T -> T5 ; WKnT = (T*Kn)^T -> T4
  {
    short8 a1[2], a2[2];
    #pragma unroll
    for (int kk=0;kk<2;kk++){
      a1[kk] = lfrag(T1, 16*w+fr, kk*32+fc);
      a2[kk] = lfrag(T2, 16*w+fr, kk*32+fc);
    }
    f32x4 cwv[4], cwk[4];
    #pragma unroll
    for (int nt=0;nt<4;nt++){ cwv[nt]=(f32x4){0.f,0.f,0.f,0.f}; cwk[nt]=(f32x4){0.f,0.f,0.f,0.f}; }
    #pragma unroll
    for (int nt=0;nt<4;nt++)
      #pragma unroll
      for (int kk=0;kk<2;kk++){
        short8 bV = lfrag(T4, 16*nt+fr, kk*32+fc);
        cwv[nt] = MM(a1[kk], bV, cwv[nt]);
        cwv[nt] = MM(a2[kk], bV, cwv[nt]);
      }
    #pragma unroll
    for (int nt=0;nt<4;nt++)
      #pragma unroll
      for (int kk=0;kk<2;kk++){
        short8 bK = lfrag(T3, 16*nt+fr, kk*32+fc);
        cwk[nt] = MM(a1[kk], bK, cwk[nt]);
        cwk[nt] = MM(a2[kk], bK, cwk[nt]);
      }
    __syncthreads();
    #pragma unroll
    for (int nt=0;nt<4;nt++){
      int n = 16*nt + nb;
      stpk(T5, n, m0, cwv[nt][0],cwv[nt][1],cwv[nt][2],cwv[nt][3]);
      stpk(T4, n, m0, cwk[nt][0],cwk[nt][1],cwk[nt][2],cwk[nt][3]);
    }
  }
  __syncthreads();

  // ---- C3: Bc -> T5, WKn -> T3, AcT(hi/lo) -> T1/T2 ; bounce WVT(T5) to global
  {
    int row = t>>2, seg = (t&3)*16;
    size_t go = cb + (size_t)row*64 + seg;
    *(short8*)(WVTg+go)   = *(const short8*)(T5 + adr(row,seg));
    *(short8*)(WVTg+go+8) = *(const short8*)(T5 + adr(row,seg+8));

    short8 aK2[2], aWKT[2];
    #pragma unroll
    for (int kk=0;kk<2;kk++){
      aK2[kk]  = lfrag(T3, 16*w+fr, kk*32+fc);
      aWKT[kk] = lfrag(T4, 16*w+fr, kk*32+fc);
    }
    f32x4 cBc[4], cWK[4], cAc[4];
    #pragma unroll
    for (int nt=0;nt<4;nt++){ cBc[nt]=(f32x4){0.f,0.f,0.f,0.f}; cWK[nt]=(f32x4){0.f,0.f,0.f,0.f}; cAc[nt]=(f32x4){0.f,0.f,0.f,0.f}; }
    #pragma unroll
    for (int nt=0;nt<4;nt++)
      #pragma unroll
      for (int kk=0;kk<2;kk++){
        short8 bWVT = lfrag(T5, 16*nt+fr, kk*32+fc);
        cBc[nt] = MM(aK2[kk], bWVT, cBc[nt]);
      }
    #pragma unroll
    for (int nt=0;nt<4;nt++)
      #pragma unroll
      for (int kk=0;kk<2;kk++){
        short8 b1 = lfrag(T1, 16*nt+fr, kk*32+fc);
        short8 b2 = lfrag(T2, 16*nt+fr, kk*32+fc);
        cWK[nt] = MM(aK2[kk], b1, cWK[nt]);
        cWK[nt] = MM(aK2[kk], b2, cWK[nt]);
      }
    #pragma unroll
    for (int nt=0;nt<4;nt++)
      #pragma unroll
      for (int kk=0;kk<2;kk++){
        short8 bK3 = lfrag(T3, 16*nt+fr, kk*32+fc);
        cAc[nt] = MM(aWKT[kk], bK3, cAc[nt]);
      }
    __syncthreads();
    #pragma unroll
    for (int nt=0;nt<4;nt++){
      int n = 16*nt + nb;
      stpk(T5, n, m0, lr*cBc[nt][0], lr*cBc[nt][1], lr*cBc[nt][2], lr*cBc[nt][3]);
      stpk(T3, n, m0, cWK[nt][0],cWK[nt][1],cWK[nt][2],cWK[nt][3]);
      float av[4];
      #pragma unroll
      for (int r=0;r<4;r++) av[r] = ((n==m0+r)?1.f:0.f) - beta*cAc[nt][r];
      stpk_hl(T1, T2, n, m0, av[0],av[1],av[2],av[3]);
    }
  }
  __syncthreads();

  // ---- C4: coalesced bounces to global
  {
    int row = t>>2, seg = (t&3)*16;
    size_t go = cb + (size_t)row*64 + seg;
    *(short8*)(AcThi+go)   = *(const short8*)(T1 + adr(row,seg));
    *(short8*)(AcThi+go+8) = *(const short8*)(T1 + adr(row,seg+8));
    *(short8*)(AcTlo+go)   = *(const short8*)(T2 + adr(row,seg));
    *(short8*)(AcTlo+go+8) = *(const short8*)(T2 + adr(row,seg+8));
    *(short8*)(Bcb+go)     = *(const short8*)(T5 + adr(row,seg));
    *(short8*)(Bcb+go+8)   = *(const short8*)(T5 + adr(row,seg+8));
    *(short8*)(WKng+go)    = *(const short8*)(T3 + adr(row,seg));
    *(short8*)(WKng+go+8)  = *(const short8*)(T3 + adr(row,seg+8));
  }
}

// ---------------- sequential chunk recurrence: M <- M*Ac + Bc (48 blocks) ----------------
__global__ __launch_bounds__(256) void seq_kernel(
    const bf16* __restrict__ AcThi, const bf16* __restrict__ AcTlo,
    const bf16* __restrict__ Bcb,
    bf16* __restrict__ Mpref, float* __restrict__ Mout)
{
  __shared__ __align__(16) char sM[4][2][2048];
  const int bh = blockIdx.x;
  const int t = threadIdx.x, w = t>>6, L = t&63;
  char* mhi = sM[w][0]; char* mlo = sM[w][1];
  const size_t cbase = (size_t)bh*NCH*4096;

  { float4 z = {0.f,0.f,0.f,0.f};
    #pragma unroll
    for (int i=0;i<2;i++){ ((float4*)mhi)[L + 64*i] = z; ((float4*)mlo)[L + 64*i] = z; } }
  { short8 z = {0,0,0,0,0,0,0,0};
    #pragma unroll
    for (int i=0;i<2;i++) ((short8*)(Mpref + cbase))[t + 256*i] = z; }

  short8 Xbh[4][2], Xbl[4][2]; float Xbc[4][4];
  short8 Ybh[4][2], Ybl[4][2]; float Ybc[4][4];

  auto loadf = [&](short8 (&fbh)[4][2], short8 (&fbl)[4][2], float (&fbc)[4][4], int c){
    size_t cb = cbase + (size_t)c*4096;
    #pragma unroll
    for (int nt=0;nt<4;nt++){
      #pragma unroll
      for (int kk=0;kk<2;kk++){
        size_t o = cb + (size_t)(16*nt + (L&15))*64 + kk*32 + (L>>4)*8;
        fbh[nt][kk] = *(const short8*)(AcThi + o);
        fbl[nt][kk] = *(const short8*)(AcTlo + o);
      }
      #pragma unroll
      for (int r=0;r<4;r++)
        fbc[nt][r] = us2f(*(const unsigned short*)(Bcb + cb + (size_t)(16*w + (L>>4)*4 + r)*64 + nt*16 + (L&15)));
    }
  };
  auto compute = [&](short8 (&fbh)[4][2], short8 (&fbl)[4][2], float (&fbc)[4][4], int c){
    short8 ah[2], al[2];
    #pragma unroll
    for (int kk=0;kk<2;kk++){
      ah[kk] = lfrag(mhi, L&15, kk*32 + (L>>4)*8);
      al[kk] = lfrag(mlo, L&15, kk*32 + (L>>4)*8);
    }
    #pragma unroll
    for (int nt=0;nt<4;nt++){
      f32x4 acc = { fbc[nt][0], fbc[nt][1], fbc[nt][2], fbc[nt][3] };
      acc = MM(ah[0], fbh[nt][0], acc);
      acc = MM(ah[1], fbh[nt][1], acc);
      acc = MM(ah[0], fbl[nt][0], acc);
      acc = MM(ah[1], fbl[nt][1], acc);
      acc = MM(al[0], fbh[nt][0], acc);
      acc = MM(al[1], fbh[nt][1], acc);
      #pragma unroll
      for (int r=0;r<4;r++){
        float f = acc[r];
        bf16 hi = __float2bfloat16(f);
        int lrow = (L>>4)*4 + r, col = nt*16 + (L&15);
        int off = ((lrow*128 + col*2) ^ ((lrow&7)<<4));
        *(bf16*)(mhi + off) = hi;
        *(bf16*)(mlo + off) = __float2bfloat16(f - bf2f(hi));
        if (c < NCH-1)
          Mpref[cbase + (size_t)(c+1)*4096 + (size_t)(16*w + lrow)*64 + col] = hi;
        else
          Mout[((size_t)bh*64 + 16*w + lrow)*64 + col] = f;
      }
    }
  };

  loadf(Xbh,Xbl,Xbc,0);
  for (int c=0;c<NCH;c+=2){
    loadf(Ybh,Ybl,Ybc,c+1);
    compute(Xbh,Xbl,Xbc,c);
    if (c+2 < NCH) loadf(Xbh,Xbl,Xbc,c+2);
    compute(Ybh,Ybl,Ybc,c+1);
  }
}

// ---------------- parallel output phase ----------------
// out = Q M0^T + Atil * U,  U = lr*WV - beta*(WKn M0^T);  Atil computed in-kernel
__global__ __launch_bounds__(256) void outphase_kernel(
    const bf16* __restrict__ kvqb, const bf16* __restrict__ Mpref,
    const bf16* __restrict__ WKng, const bf16* __restrict__ WVTb,
    const float* __restrict__ lr_scale, bf16* __restrict__ attn)
{
  __shared__ __align__(16) char sUT[8192];
  __shared__ __align__(16) char sAT[8192];
  const int c = blockIdx.x, bh = blockIdx.y;
  const int b = bh / H_, h = bh % H_;
  const int t = threadIdx.x, w = t>>6, L = t&63;
  const size_t PS = (size_t)B_*H_*S_*HD_;
  const size_t cb = ((size_t)bh*NCH + c)*4096;
  const size_t base_k = (size_t)bh*S_*HD_ + (size_t)c*CH*HD_;
  const bf16* Kg = kvqb + base_k;
  const bf16* Qg = kvqb + 2*PS + base_k;
  const float lr = 0.2f/(1.f + __expf(-lr_scale[h]));
  const float beta = 1.f + lr;
  const int fr = L&15, fc = (L>>4)*8;
  const int m0 = 16*w + (L>>4)*4;
  const int nb = L&15;

  // Atil tile: Z[t][i] = (i<t)? (Q Kn^T)[t][i] : 0   via TILE(Kn,Q) + packed C^T store
  {
    short8 aKn[2];
    #pragma unroll
    for (int kk=0;kk<2;kk++) aKn[kk] = gfrag(Kg, 16*w+fr, kk*32+fc);
    #pragma unroll
    for (int nt=0;nt<4;nt++){
      f32x4 cat = (f32x4){0.f,0.f,0.f,0.f};
      #pragma unroll
      for (int kk=0;kk<2;kk++) cat = MM(aKn[kk], gfrag(Qg, 16*nt+fr, kk*32+fc), cat);
      int n = 16*nt + nb;
      float v[4];
      #pragma unroll
      for (int r=0;r<4;r++) v[r] = (m0+r < n)? cat[r] : 0.f;
      stpk(sAT, n, m0, v[0],v[1],v[2],v[3]);
    }
  }

  short8 mb[4][2], qa[2], wa[2];
  #pragma unroll
  for (int kk=0;kk<2;kk++){
    qa[kk] = gfrag(Qg, 16*w+fr, kk*32+fc);
    wa[kk] = *(const short8*)(WKng + cb + (size_t)(16*w + fr)*64 + kk*32 + fc);
  }
  #pragma unroll
  for (int nt=0;nt<4;nt++)
    #pragma unroll
    for (int kk=0;kk<2;kk++)
      mb[nt][kk] = *(const short8*)(Mpref + cb + (size_t)(16*nt + fr)*64 + kk*32 + fc);
  f32x4 aout[4], ap[4];
  #pragma unroll
  for (int nt=0;nt<4;nt++){ aout[nt]=(f32x4){0.f,0.f,0.f,0.f}; ap[nt]=(f32x4){0.f,0.f,0.f,0.f}; }
  #pragma unroll
  for (int nt=0;nt<4;nt++)
    #pragma unroll
    for (int kk=0;kk<2;kk++){
      aout[nt] = MM(qa[kk], mb[nt][kk], aout[nt]);
      ap[nt]   = MM(wa[kk], mb[nt][kk], ap[nt]);
    }
  #pragma unroll
  for (int nt=0;nt<4;nt++){
    s16x4 wv4 = *(const s16x4*)(WVTb + cb + (size_t)(nt*16 + (L&15))*64 + 16*w + (L>>4)*4);
    short us[4];
    #pragma unroll
    for (int r=0;r<4;r++){
      float wv = us2f((unsigned short)wv4[r]);
      us[r] = f2s(lr*wv - beta*ap[nt][r]);
    }
    int d = nt*16 + (L&15);
    int i0 = 16*w + (L>>4)*4;
    s16x4 pk = { us[0], us[1], us[2], us[3] };
    *(s16x4*)(sUT + adr(d, i0)) = pk;
  }
  __syncthreads();
  short8 ta[2], ub[4][2];
  #pragma unroll
  for (int kk=0;kk<2;kk++)
    ta[kk] = lfrag(sAT, 16*w+fr, kk*32+fc);
  #pragma unroll
  for (int nt=0;nt<4;nt++)
    #pragma unroll
    for (int kk=0;kk<2;kk++)
      ub[nt][kk] = lfrag(sUT, 16*nt + fr, kk*32 + fc);
  #pragma unroll
  for (int nt=0;nt<4;nt++)
    #pragma unroll
    for (int kk=0;kk<2;kk++)
      aout[nt] = MM(ta[kk], ub[nt][kk], aout[nt]);
  #pragma unroll
  for (int nt=0;nt<4;nt++)
    #pragma unroll
    for (int r=0;r<4;r++)
      attn[((size_t)b*S_ + (size_t)c*CH + 16*w + (L>>4)*4 + r)*P_ + h*HD_ + nt*16 + (L&15)]
        = __float2bfloat16(aout[nt][r]);
}

extern "C" void kernel_launch(void* const* d_in, const int* in_sizes, int n_in,
                              void* d_out, int out_size, void* d_ws, size_t ws_size,
                              hipStream_t stream)
{
  const float* x     = (const float*)d_in[0];
  const float* ln_g  = (const float*)d_in[1];
  const float* ln_b  = (const float*)d_in[2];
  const float* Wk    = (const float*)d_in[3];
  const float* Wv    = (const float*)d_in[4];
  const float* Wq    = (const float*)d_in[5];
  const float* km_w1 = (const float*)d_in[6];  const float* km_b1 = (const float*)d_in[7];
  const float* km_w2 = (const float*)d_in[8];  const float* km_b2 = (const float*)d_in[9];
  const float* vm_w1 = (const float*)d_in[10]; const float* vm_b1 = (const float*)d_in[11];
  const float* vm_w2 = (const float*)d_in[12]; const float* vm_b2 = (const float*)d_in[13];
  const float* qm_w1 = (const float*)d_in[14]; const float* qm_b1 = (const float*)d_in[15];
  const float* qm_w2 = (const float*)d_in[16]; const float* qm_b2 = (const float*)d_in[17];
  const float* lnk_g = (const float*)d_in[18]; const float* lnk_b = (const float*)d_in[19];
  const float* lnv_g = (const float*)d_in[20]; const float* lnv_b = (const float*)d_in[21];
  const float* lnq_g = (const float*)d_in[22]; const float* lnq_b = (const float*)d_in[23];
  const float* Wo    = (const float*)d_in[24];
  const float* lr_sc = (const float*)d_in[25];
  const float* Wg    = (const float*)d_in[26];
  const float* bg    = (const float*)d_in[27];

  const size_t CHB = (size_t)BH*NCH*4096;

  char* ws = (char*)d_ws;
  size_t o = 0;
  bf16* xnb   = (bf16*)(ws + o); o += (size_t)M_*D_*2;
  bf16* xb    = (bf16*)(ws + o); o += (size_t)M_*D_*2;
  bf16* Hb    = (bf16*)(ws + o); o += (size_t)M_*576*2;
  bf16* kvqb  = (bf16*)(ws + o); o += (size_t)3*M_*P_*2;
  bf16* attn  = (bf16*)(ws + o); o += (size_t)M_*P_*2;
  size_t o_p = o;
  bf16* AcThi = (bf16*)(ws + o); o += CHB*2;
  bf16* AcTlo = (bf16*)(ws + o); o += CHB*2;
  bf16* Bcb   = (bf16*)(ws + o); o += CHB*2;
  bf16* WVTb  = (bf16*)(ws + o); o += CHB*2;
  bf16* WKng  = (bf16*)(ws + o); o += CHB*2;
  bf16* Mpref = (bf16*)(ws + o); o += CHB*2;
  bf16* Whb   = (bf16*)(ws + o); o += (size_t)640*768*2;
  bf16* Wkvqb = (bf16*)(ws + o); o += (size_t)2304*960*2;
  bf16* Wob   = (bf16*)(ws + o); o += (size_t)768*768*2;
  bf16* Wgb   = (bf16*)(ws + o); o += (size_t)768*768*2;
  float* biasb= (float*)(ws + o); o += 3264*4;
  // G2 overlays AcThi+AcTlo (dead after seq; outphase doesn't touch them)
  float* G2   = (float*)(ws + o_p);

  float* outF = (float*)d_out;
  float* Mout = outF + (size_t)M_*D_;

  pack_all_kernel<<<15181, 256, 0, stream>>>(
      km_w1, vm_w1, qm_w1, Wk, Wv, Wq, km_w2, vm_w2, qm_w2, Wo, Wg,
      km_b1, vm_b1, qm_b1, km_b2, vm_b2, qm_b2,
      lnk_g, lnv_g, lnq_g, lnk_b, lnv_b, lnq_b,
      Whb, Wkvqb, Wob, Wgb, biasb);

  ln_in_kernel<<<M_, 256, 0, stream>>>(x, ln_g, ln_b, xnb, xb);

  gemm_kernel<0><<<dim3(64,5,1), 256, 0, stream>>>(xnb, 768, 768, nullptr, 0, 0, 0,
                                                   Whb, 768, 640, biasb, nullptr, nullptr, nullptr, Hb, 576);
  gemm_kernel<1><<<dim3(64,6,3), 256, 0, stream>>>(xnb, 768, 768, Hb, 576, 192, 192,
                                                   Wkvqb, 960, 768, biasb + 576, nullptr,
                                                   biasb + 2880, biasb + 3072, kvqb, 768);

  prep_kernel<<<dim3(NCH, BH), 256, 0, stream>>>(kvqb, lr_sc, WKng, WVTb, AcThi, AcTlo, Bcb);
  seq_kernel<<<BH, 256, 0, stream>>>(AcThi, AcTlo, Bcb, Mpref, Mout);
  outphase_kernel<<<dim3(NCH, BH), 256, 0, stream>>>(kvqb, Mpref, WKng, WVTb, lr_sc, attn);

  // G2 = x @ Wg^T (fp32), then fused out = (attn @ Wo^T) * sigmoid(G2 + bg)
  gemm_kernel<2><<<dim3(64,6,1), 256, 0, stream>>>(xb, 768, 768, nullptr, 0, 0, 0,
                                                   Wgb, 768, 768, nullptr, nullptr, nullptr, nullptr, G2, 768);
  gemm_kernel<3><<<dim3(64,6,1), 256, 0, stream>>>(attn, 768, 768, nullptr, 0, 0, 0,
                                                   Wob, 768, 768, bg, G2, nullptr, nullptr, outF, 768);
}